// Round 3
// baseline (1000.993 us; speedup 1.0000x reference)
//
#include <hip/hip_runtime.h>
#include <hip/hip_bf16.h>

// DenseDSSnetwork: 4-layer DSS-GIN over 4096 node-deleted subgraphs + graph branch.
// Inputs fp32, OUTPUT fp32 [64,10]. bf16 MFMA (16x16x32), fp32 accumulate.
// eps folded into adjacency diagonal: t = (adj + (1+eps)I) @ x.
// W B-fragments read directly from global (L1-resident). LDS 40KB -> 4 blocks/CU.

typedef __bf16 bf16x8 __attribute__((ext_vector_type(8)));
typedef float f32x4 __attribute__((ext_vector_type(4)));
typedef unsigned short us8 __attribute__((ext_vector_type(8)));
typedef unsigned short us4 __attribute__((ext_vector_type(4)));

__device__ __forceinline__ unsigned short f2b(float f) {
  unsigned u = __builtin_bit_cast(unsigned, f);
  u += 0x7FFFu + ((u >> 16) & 1u);            // RNE
  return (unsigned short)(u >> 16);
}
__device__ __forceinline__ float b2f(unsigned short h) {
  return __builtin_bit_cast(float, (unsigned)h << 16);
}
__device__ __forceinline__ f32x4 mm(bf16x8 a, bf16x8 b, f32x4 c) {
  return __builtin_amdgcn_mfma_f32_16x16x32_bf16(a, b, c, 0, 0, 0);
}
// fragment load from row-major LDS [rows][Kelems] bf16, XOR-swizzled rows
__device__ __forceinline__ bf16x8 frag(const char* base, int row, int Kelems, int k0) {
  int off = (row * Kelems + k0) * 2;
  off ^= (row & 7) << 4;
  return *(const bf16x8*)(base + off);
}
__device__ __forceinline__ float lk(float v) { return v > 0.f ? v : 0.01f * v; }

// fp32 -> bf16 cast, vectorized (for adj / oadj)
__global__ __launch_bounds__(256) void k_cast(const float* __restrict__ src,
                                              unsigned short* __restrict__ dst, int n4) {
  int i = blockIdx.x * 256 + threadIdx.x;
  if (i < n4) {
    float4 v = ((const float4*)src)[i];
    us4 h; h.x = f2b(v.x); h.y = f2b(v.y); h.z = f2b(v.z); h.w = f2b(v.w);
    ((us4*)dst)[i] = h;
  }
}

// Weight prep: W[k][n] fp32 -> Wt[n][k] bf16, 16 matrices (l*4 + {gW1,gW2,sW1,sW2})
__global__ __launch_bounds__(256) void k_prep(const float* __restrict__ g1,
    const float* __restrict__ g2, const float* __restrict__ s1,
    const float* __restrict__ s2, unsigned short* __restrict__ wt) {
  int b = blockIdx.x;              // 0..15
  int l = b >> 2, j = b & 3;
  const float* src = (j == 0 ? g1 : j == 1 ? g2 : j == 2 ? s1 : s2) + l * 16384;
  unsigned short* dst = wt + b * 16384;
  for (int e = threadIdx.x; e < 16384; e += 256) {
    int n = e >> 7, k = e & 127;
    dst[e] = f2b(src[k * 128 + n]);
  }
}

// x_sum[g,n,d] = mean over 64 subgraphs; FP32IN: layer-0 fp32 x, else bf16 xw
template<bool FP32IN>
__global__ __launch_bounds__(128) void k_segmean(const void* __restrict__ xsrc,
                                                 float* __restrict__ xsum) {
  int gb = blockIdx.x;             // g*64+n
  int g = gb >> 6;
  size_t base = ((size_t)g * 64) * 8192 + (size_t)(gb & 63) * 128 + threadIdx.x;
  float s = 0.f;
  if (FP32IN) {
    const float* p = (const float*)xsrc + base;
    #pragma unroll 8
    for (int j = 0; j < 64; ++j) s += p[(size_t)j * 8192];
  } else {
    const unsigned short* p = (const unsigned short*)xsrc + base;
    #pragma unroll 8
    for (int j = 0; j < 64; ++j) s += b2f(p[(size_t)j * 8192]);
  }
  xsum[(size_t)gb * 128 + threadIdx.x] = s * (1.0f / 64.0f);
}

// Fused GIN: h = mask*( leaky(((adj+ep1*I)@x)@W1 + b1) @ W2 + b2 ), + BN partials.
// One block per (sub)graph, 256 threads = 4 waves. LDS 40KB.
template<bool FP32IN>
__global__ __launch_bounds__(256, 4) void k_gin(const void* __restrict__ xsrc,
    const unsigned short* __restrict__ adjb, const unsigned short* __restrict__ W1t,
    const unsigned short* __restrict__ W2t, const float* __restrict__ b1,
    const float* __restrict__ b2, const float* __restrict__ epsp,
    unsigned short* __restrict__ hout, float* __restrict__ psum,
    float* __restrict__ psq, int masked) {
  __shared__ __align__(16) char lds[40960];
  char* ldsAdj = lds;              // 8KB : bf16 [64][64]  swz (adj + ep1*I)
  char* ldsB   = lds + 8192;       // 16KB: x^T [128][64] swz, then u [64][128] swz
  char* ldsC   = lds + 24576;      // 16KB: x_rm [64][128] linear, then t, then h (swz)
  float* ldsR  = (float*)lds;      // reduce scratch (overlaps ldsAdj, dead by then)

  const int tid = threadIdx.x;
  const int bid = blockIdx.x;
  const float ep1 = 1.0f + epsp[0];
  const int del = masked ? (bid & 63) : -1;

  // ---- stage adj bf16 (+ep1 on diagonal) ----
  {
    const unsigned short* ag = adjb + (size_t)bid * 4096;
    unsigned short ep1b = f2b(ep1);
    for (int e = tid * 8; e < 4096; e += 2048) {
      us8 v = *(const us8*)(ag + e);
      int row = e >> 6, col = e & 63;
      int j = row - col;
      if (j >= 0 && j < 8) v[j] = ep1b;    // adj diag is 0 -> overwrite with ep1
      *(us8*)(ldsAdj + ((e << 1) ^ ((row & 7) << 4))) = v;
    }
  }
  // ---- stage x row-major bf16 into ldsC (linear) ----
  if (FP32IN) {
    const float* xg = (const float*)xsrc + (size_t)bid * 8192;
    for (int e = tid * 4; e < 8192; e += 1024) {
      float4 v = *(const float4*)(xg + e);
      us4 h; h.x = f2b(v.x); h.y = f2b(v.y); h.z = f2b(v.z); h.w = f2b(v.w);
      *(us4*)(ldsC + e * 2) = h;
    }
  } else {
    const unsigned short* xg = (const unsigned short*)xsrc + (size_t)bid * 8192;
    for (int e = tid * 8; e < 8192; e += 2048)
      *(us8*)(ldsC + e * 2) = *(const us8*)(xg + e);
  }
  __syncthreads();

  // ---- transpose x_rm -> ldsB = x^T [128][64] swz ----
  {
    int d = tid & 127, mg = (tid >> 7) * 32;
    #pragma unroll
    for (int mb = 0; mb < 32; mb += 8) {
      us8 v;
      #pragma unroll
      for (int j = 0; j < 8; ++j)
        v[j] = *(const unsigned short*)(ldsC + ((mg + mb + j) << 8) + (d << 1));
      int off = ((d << 7) + ((mg + mb) << 1)) ^ ((d & 7) << 4);
      *(us8*)(ldsB + off) = v;
    }
  }
  __syncthreads();

  const int wv = tid >> 6, ln = tid & 63;
  const int lr = ln & 15, lkh = ln >> 4;
  const int arow = wv * 16 + lr;

  // ---- mm1: t = (adj+ep1*I) @ x -> ldsC [64][128] swz (x_rm dead) ----
  #pragma unroll
  for (int nt = 0; nt < 8; ++nt) {
    f32x4 acc = {0.f, 0.f, 0.f, 0.f};
    #pragma unroll
    for (int k0 = 0; k0 < 64; k0 += 32) {
      bf16x8 a = frag(ldsAdj, arow, 64, k0 + lkh * 8);
      bf16x8 b = frag(ldsB, nt * 16 + lr, 64, k0 + lkh * 8);
      acc = mm(a, b, acc);
    }
    int col = nt * 16 + lr;
    #pragma unroll
    for (int r = 0; r < 4; ++r) {
      int row = wv * 16 + lkh * 4 + r;
      *(unsigned short*)(ldsC + (((row << 8) + (col << 1)) ^ ((row & 7) << 4))) = f2b(acc[r]);
    }
  }
  __syncthreads();

  // ---- mm2: u = leaky(t @ W1 + b1); W1 B-frags from global (L1) ----
  float uf[8][4];
  #pragma unroll
  for (int nt = 0; nt < 8; ++nt) {
    f32x4 acc = {0.f, 0.f, 0.f, 0.f};
    #pragma unroll
    for (int k0 = 0; k0 < 128; k0 += 32) {
      bf16x8 a = frag(ldsC, arow, 128, k0 + lkh * 8);
      bf16x8 b = *(const bf16x8*)(W1t + (size_t)(nt * 16 + lr) * 128 + k0 + lkh * 8);
      acc = mm(a, b, acc);
    }
    float bb = b1[nt * 16 + lr];
    #pragma unroll
    for (int r = 0; r < 4; ++r) uf[nt][r] = lk(acc[r] + bb);
  }
  // write u -> ldsB [64][128] swz (x^T dead)
  #pragma unroll
  for (int nt = 0; nt < 8; ++nt) {
    int col = nt * 16 + lr;
    #pragma unroll
    for (int r = 0; r < 4; ++r) {
      int row = wv * 16 + lkh * 4 + r;
      *(unsigned short*)(ldsB + (((row << 8) + (col << 1)) ^ ((row & 7) << 4))) = f2b(uf[nt][r]);
    }
  }
  __syncthreads();

  // ---- mm3: h = u @ W2 + b2, mask deleted row; h -> ldsC (t dead) ----
  #pragma unroll
  for (int nt = 0; nt < 8; ++nt) {
    f32x4 acc = {0.f, 0.f, 0.f, 0.f};
    #pragma unroll
    for (int k0 = 0; k0 < 128; k0 += 32) {
      bf16x8 a = frag(ldsB, arow, 128, k0 + lkh * 8);
      bf16x8 b = *(const bf16x8*)(W2t + (size_t)(nt * 16 + lr) * 128 + k0 + lkh * 8);
      acc = mm(a, b, acc);
    }
    float bb = b2[nt * 16 + lr];
    int col = nt * 16 + lr;
    #pragma unroll
    for (int r = 0; r < 4; ++r) {
      int row = wv * 16 + lkh * 4 + r;
      float v = acc[r] + bb;
      if (row == del) v = 0.f;
      *(unsigned short*)(ldsC + (((row << 8) + (col << 1)) ^ ((row & 7) << 4))) = f2b(v);
    }
  }
  __syncthreads();

  // ---- global write h + BN per-feature partials ----
  size_t gbase = (size_t)bid * 8192;
  for (int e = tid * 8; e < 8192; e += 2048) {
    int m = e >> 7, d0 = e & 127;
    us8 v = *(const us8*)(ldsC + (((m << 8) + (d0 << 1)) ^ ((m & 7) << 4)));
    *(us8*)(hout + gbase + e) = v;
  }
  {
    int d = tid & 127, half = tid >> 7;
    float sm = 0.f, sq = 0.f;
    for (int m = half * 32; m < half * 32 + 32; ++m) {
      float v = b2f(*(const unsigned short*)(ldsC + (((m << 8) + (d << 1)) ^ ((m & 7) << 4))));
      sm += v; sq += v * v;
    }
    ldsR[tid] = sm; ldsR[256 + tid] = sq;
    __syncthreads();
    if (tid < 128) {
      psum[(size_t)bid * 128 + tid] = ldsR[tid] + ldsR[tid + 128];
      psq[(size_t)bid * 128 + tid]  = ldsR[256 + tid] + ldsR[256 + tid + 128];
    }
  }
}

// Finalize BN for both branches into fused scale/shift: hn = h*A + B
__global__ __launch_bounds__(256) void k_bnfin(const float* __restrict__ p1s,
    const float* __restrict__ p1q, const float* __restrict__ p2s,
    const float* __restrict__ p2q, const float* __restrict__ gam1,
    const float* __restrict__ bet1, const float* __restrict__ gam2,
    const float* __restrict__ bet2, float* __restrict__ bnA, float* __restrict__ bnB,
    float* __restrict__ bnsA, float* __restrict__ bnsB) {
  __shared__ float red[512];
  __shared__ float red2[128];
  int d = blockIdx.x;              // feature 0..127
  int t = threadIdx.x;
  float s = 0.f, q = 0.f;
  for (int j = t; j < 4096; j += 256) { s += p1s[(size_t)j * 128 + d]; q += p1q[(size_t)j * 128 + d]; }
  red[t] = s; red[256 + t] = q;
  if (t < 64) { red2[t] = p2s[(size_t)t * 128 + d]; red2[64 + t] = p2q[(size_t)t * 128 + d]; }
  __syncthreads();
  for (int w = 128; w > 0; w >>= 1) {
    if (t < w) { red[t] += red[t + w]; red[256 + t] += red[256 + t + w]; }
    __syncthreads();
  }
  for (int w = 32; w > 0; w >>= 1) {
    if (t < w) { red2[t] += red2[t + w]; red2[64 + t] += red2[64 + t + w]; }
    __syncthreads();
  }
  if (t == 0) {
    const float cnt1 = 4096.0f * 63.0f;
    float mean = red[0] / cnt1;
    float var = red[256] / cnt1 - mean * mean;
    float A = gam1[d] * rsqrtf(var + 1e-5f);
    bnA[d] = A; bnB[d] = bet1[d] - mean * A;
    const float cnt2 = 4096.0f;
    float mean2 = red2[0] / cnt2;
    float var2 = red2[64] / cnt2 - mean2 * mean2;
    float A2 = gam2[d] * rsqrtf(var2 + 1e-5f);
    bnsA[d] = A2; bnsB[d] = bet2[d] - mean2 * A2;
  }
}

// x_new = leaky( where(valid, BN1(h1), 0) + BN2(h2[g]) ); optional pool fusion
template<int WRITE_X, int DO_POOL>
__global__ __launch_bounds__(256) void k_combine(const unsigned short* __restrict__ h1,
    const unsigned short* __restrict__ h2, const float* __restrict__ bnA,
    const float* __restrict__ bnB, const float* __restrict__ bnsA,
    const float* __restrict__ bnsB, unsigned short* __restrict__ xo,
    float* __restrict__ pp) {
  __shared__ float A1[128], B1[128], A2[128], B2[128];
  __shared__ float pl[16][128];
  int tid = threadIdx.x;
  if (tid < 128) { A1[tid] = bnA[tid]; B1[tid] = bnB[tid]; A2[tid] = bnsA[tid]; B2[tid] = bnsB[tid]; }
  __syncthreads();
  int s = blockIdx.x, g = s >> 6, del = s & 63;
  size_t sb = (size_t)s * 8192, gb = (size_t)g * 8192;
  float ps[8] = {0.f, 0.f, 0.f, 0.f, 0.f, 0.f, 0.f, 0.f};
  for (int e = tid * 8; e < 8192; e += 2048) {
    int m = e >> 7, d0 = e & 127;
    us8 a = *(const us8*)(h1 + sb + e);
    us8 b = *(const us8*)(h2 + gb + e);
    us8 o;
    #pragma unroll
    for (int j = 0; j < 8; ++j) {
      int d = d0 + j;
      float hv = (m == del) ? 0.f : fmaf(b2f(a[j]), A1[d], B1[d]);
      float h2v = fmaf(b2f(b[j]), A2[d], B2[d]);
      float vv = lk(hv + h2v);
      o[j] = f2b(vv);
      if (DO_POOL) ps[j] += vv;
    }
    if (WRITE_X) *(us8*)(xo + sb + e) = o;
  }
  if (DO_POOL) {
    int rg = tid >> 4, c8 = (tid & 15) * 8;
    #pragma unroll
    for (int j = 0; j < 8; ++j) pl[rg][c8 + j] = ps[j];
    __syncthreads();
    if (tid < 128) {
      float s2 = 0.f;
      #pragma unroll
      for (int r = 0; r < 16; ++r) s2 += pl[r][tid];
      pp[(size_t)blockIdx.x * 128 + tid] = s2 * (1.0f / 63.0f);  // / num_nodes
    }
  }
}

// final readout MLP per graph, fp32 out
__global__ __launch_bounds__(256) void k_final(const float* __restrict__ pp,
    const float* __restrict__ W1, const float* __restrict__ b1,
    const float* __restrict__ W2, const float* __restrict__ b2,
    float* __restrict__ out) {
  __shared__ float hg[128];
  __shared__ float z[256];
  int g = blockIdx.x, t = threadIdx.x;
  if (t < 128) {
    float s = 0.f;
    for (int p = 0; p < 64; ++p) s += pp[(size_t)(g * 64 + p) * 128 + t];
    hg[t] = s * (1.0f / 64.0f);
  }
  __syncthreads();
  float a = b1[t];
  for (int d = 0; d < 128; ++d) a = fmaf(hg[d], W1[d * 256 + t], a);
  z[t] = lk(a);
  __syncthreads();
  if (t < 10) {
    float o = b2[t];
    for (int j = 0; j < 256; ++j) o = fmaf(z[j], W2[j * 10 + t], o);
    out[g * 10 + t] = o;
  }
}

extern "C" void kernel_launch(void* const* d_in, const int* in_sizes, int n_in,
                              void* d_out, int out_size, void* d_ws, size_t ws_size,
                              hipStream_t stream) {
  (void)in_sizes; (void)n_in; (void)out_size; (void)ws_size;
  const float* x    = (const float*)d_in[0];
  const float* adj  = (const float*)d_in[1];
  const float* oadj = (const float*)d_in[2];
  const float* gW1  = (const float*)d_in[3];
  const float* gb1  = (const float*)d_in[4];
  const float* gW2  = (const float*)d_in[5];
  const float* gb2  = (const float*)d_in[6];
  const float* geps = (const float*)d_in[7];
  const float* sW1  = (const float*)d_in[8];
  const float* sb1  = (const float*)d_in[9];
  const float* sW2  = (const float*)d_in[10];
  const float* sb2  = (const float*)d_in[11];
  const float* seps = (const float*)d_in[12];
  const float* bng  = (const float*)d_in[13];
  const float* bnb  = (const float*)d_in[14];
  const float* bnsg = (const float*)d_in[15];
  const float* bnsb = (const float*)d_in[16];
  const float* fW1  = (const float*)d_in[17];
  const float* fb1  = (const float*)d_in[18];
  const float* fW2  = (const float*)d_in[19];
  const float* fb2  = (const float*)d_in[20];
  float* out = (float*)d_out;

  char* w = (char*)d_ws;
  unsigned short* xw   = (unsigned short*)w; w += 67108864;   // x bf16 [4096][64][128]
  unsigned short* h1   = (unsigned short*)w; w += 67108864;   // h1 bf16
  unsigned short* adjb = (unsigned short*)w; w += 33554432;   // adj bf16 [4096][64][64]
  unsigned short* h2   = (unsigned short*)w; w += 1048576;    // h2 bf16 [64][64][128]
  unsigned short* oadjb= (unsigned short*)w; w += 524288;     // oadj bf16
  unsigned short* wt   = (unsigned short*)w; w += 524288;     // 16x bf16 [128][128] W^T
  float* xsum = (float*)w;          w += 2097152;             // fp32 [64][64][128]
  float* p1s  = (float*)w;          w += 2097152;
  float* p1q  = (float*)w;          w += 2097152;
  float* p2s  = (float*)w;          w += 32768;
  float* p2q  = (float*)w;          w += 32768;
  float* bnA  = (float*)w;          w += 512;
  float* bnB  = (float*)w;          w += 512;
  float* bnsA = (float*)w;          w += 512;
  float* bnsB = (float*)w;          w += 512;
  float* pp   = (float*)w;          w += 2097152;             // pool partials [4096][128]

  k_prep<<<16, 256, 0, stream>>>(gW1, gW2, sW1, sW2, wt);
  k_cast<<<16384, 256, 0, stream>>>(adj, adjb, 4194304);
  k_cast<<<256, 256, 0, stream>>>(oadj, oadjb, 65536);

  for (int i = 0; i < 4; ++i) {
    const void* xi = (i == 0) ? (const void*)x : (const void*)xw;
    if (i == 0) k_segmean<true><<<4096, 128, 0, stream>>>(xi, xsum);
    else        k_segmean<false><<<4096, 128, 0, stream>>>(xi, xsum);
    if (i == 0) k_gin<true><<<4096, 256, 0, stream>>>(xi, adjb,
        wt + (i * 4 + 0) * 16384, wt + (i * 4 + 1) * 16384,
        gb1 + i * 128, gb2 + i * 128, geps + i, h1, p1s, p1q, 1);
    else        k_gin<false><<<4096, 256, 0, stream>>>(xi, adjb,
        wt + (i * 4 + 0) * 16384, wt + (i * 4 + 1) * 16384,
        gb1 + i * 128, gb2 + i * 128, geps + i, h1, p1s, p1q, 1);
    k_gin<true><<<64, 256, 0, stream>>>(xsum, oadjb,
        wt + (i * 4 + 2) * 16384, wt + (i * 4 + 3) * 16384,
        sb1 + i * 128, sb2 + i * 128, seps + i, h2, p2s, p2q, 0);
    k_bnfin<<<128, 256, 0, stream>>>(p1s, p1q, p2s, p2q, bng + i * 128,
        bnb + i * 128, bnsg + i * 128, bnsb + i * 128, bnA, bnB, bnsA, bnsB);
    if (i < 3) k_combine<1, 0><<<4096, 256, 0, stream>>>(h1, h2, bnA, bnB, bnsA, bnsB, xw, pp);
    else       k_combine<0, 1><<<4096, 256, 0, stream>>>(h1, h2, bnA, bnB, bnsA, bnsB, xw, pp);
  }
  k_final<<<64, 256, 0, stream>>>(pp, fW1, fb1, fW2, fb2, out);
}

// Round 4
// 582.050 us; speedup vs baseline: 1.7198x; 1.7198x over previous
//
#include <hip/hip_runtime.h>
#include <hip/hip_bf16.h>

// DenseDSSnetwork: 4-layer DSS-GIN over 4096 node-deleted subgraphs + graph branch.
// Inputs fp32, OUTPUT fp32 [64,10]. bf16 MFMA (16x16x32), fp32 accumulate.
// k_gin: 8 waves, wave w owns output cols w*16..+15; W1/W2 fragments live in
// REGISTERS (4+4 bf16x8/lane), loaded once per block. eps folded into adj diag.

typedef __bf16 bf16x8 __attribute__((ext_vector_type(8)));
typedef float f32x4 __attribute__((ext_vector_type(4)));
typedef unsigned short us8 __attribute__((ext_vector_type(8)));
typedef unsigned short us4 __attribute__((ext_vector_type(4)));

__device__ __forceinline__ unsigned short f2b(float f) {
  unsigned u = __builtin_bit_cast(unsigned, f);
  u += 0x7FFFu + ((u >> 16) & 1u);            // RNE
  return (unsigned short)(u >> 16);
}
__device__ __forceinline__ float b2f(unsigned short h) {
  return __builtin_bit_cast(float, (unsigned)h << 16);
}
__device__ __forceinline__ f32x4 mm(bf16x8 a, bf16x8 b, f32x4 c) {
  return __builtin_amdgcn_mfma_f32_16x16x32_bf16(a, b, c, 0, 0, 0);
}
// fragment load from row-major LDS [rows][Kelems] bf16, XOR-swizzled rows
__device__ __forceinline__ bf16x8 frag(const char* base, int row, int Kelems, int k0) {
  int off = (row * Kelems + k0) * 2;
  off ^= (row & 7) << 4;
  return *(const bf16x8*)(base + off);
}
__device__ __forceinline__ float lk(float v) { return v > 0.f ? v : 0.01f * v; }

// fp32 -> bf16 cast, vectorized
__global__ __launch_bounds__(256) void k_cast(const float* __restrict__ src,
                                              unsigned short* __restrict__ dst, int n4) {
  int i = blockIdx.x * 256 + threadIdx.x;
  if (i < n4) {
    float4 v = ((const float4*)src)[i];
    us4 h; h.x = f2b(v.x); h.y = f2b(v.y); h.z = f2b(v.z); h.w = f2b(v.w);
    ((us4*)dst)[i] = h;
  }
}

// Weight prep: W[k][n] fp32 -> Wt[n][k] bf16, 16 matrices (l*4 + {gW1,gW2,sW1,sW2})
__global__ __launch_bounds__(256) void k_prep(const float* __restrict__ g1,
    const float* __restrict__ g2, const float* __restrict__ s1,
    const float* __restrict__ s2, unsigned short* __restrict__ wt) {
  int b = blockIdx.x;              // 0..15
  int l = b >> 2, j = b & 3;
  const float* src = (j == 0 ? g1 : j == 1 ? g2 : j == 2 ? s1 : s2) + l * 16384;
  unsigned short* dst = wt + b * 16384;
  for (int e = threadIdx.x; e < 16384; e += 256) {
    int n = e >> 7, k = e & 127;
    dst[e] = f2b(src[k * 128 + n]);
  }
}

// x_sum[g,n,d] = mean over 64 subgraphs (bf16 in, fp32 out)
__global__ __launch_bounds__(128) void k_segmean(const unsigned short* __restrict__ xsrc,
                                                 float* __restrict__ xsum) {
  int gb = blockIdx.x;             // g*64+n
  int g = gb >> 6;
  const unsigned short* p = xsrc + ((size_t)g * 64) * 8192 + (size_t)(gb & 63) * 128 + threadIdx.x;
  float s = 0.f;
  #pragma unroll 8
  for (int j = 0; j < 64; ++j) s += b2f(p[(size_t)j * 8192]);
  xsum[(size_t)gb * 128 + threadIdx.x] = s * (1.0f / 64.0f);
}

// Fused GIN: h = mask*( leaky(((adj+ep1*I)@x)@W1 + b1) @ W2 + b2 ), + BN partials.
// 512 threads = 8 waves; wave w owns output cols w*16..+15. W1/W2 in registers.
template<bool FP32IN>
__global__ __launch_bounds__(512, 4) void k_gin(const void* __restrict__ xsrc,
    const unsigned short* __restrict__ adjb, const unsigned short* __restrict__ W1t,
    const unsigned short* __restrict__ W2t, const float* __restrict__ b1,
    const float* __restrict__ b2, const float* __restrict__ epsp,
    unsigned short* __restrict__ hout, float* __restrict__ psum,
    float* __restrict__ psq, int masked) {
  __shared__ __align__(16) char lds[40960];
  char* ldsAdj = lds;              // 8KB : bf16 [64][64] swz (adj + ep1*I)
  char* ldsB   = lds + 8192;       // 16KB: x^T [128][64] swz, then u [64][128] swz
  char* ldsC   = lds + 24576;      // 16KB: x_rm [64][128] linear, then t, then h (swz)
  float* ldsR  = (float*)lds;      // reduce scratch (overlaps ldsAdj, dead by then)

  const int tid = threadIdx.x;
  const int bid = blockIdx.x;
  const int wv = tid >> 6, ln = tid & 63;
  const int lr = ln & 15, lkh = ln >> 4;
  const int wrow = wv * 16 + lr;   // this lane's output column
  const float ep1 = 1.0f + epsp[0];
  const int del = masked ? (bid & 63) : -1;

  // ---- W fragments into registers (one-time, hidden behind staging) ----
  bf16x8 w1f[4], w2f[4];
  #pragma unroll
  for (int kk = 0; kk < 4; ++kk) {
    w1f[kk] = *(const bf16x8*)(W1t + (size_t)wrow * 128 + kk * 32 + lkh * 8);
    w2f[kk] = *(const bf16x8*)(W2t + (size_t)wrow * 128 + kk * 32 + lkh * 8);
  }
  const float bb1 = b1[wrow], bb2 = b2[wrow];

  // ---- stage adj bf16 (+ep1 on diagonal): 4096 elems, 512 thr x us8 ----
  {
    const unsigned short* ag = adjb + (size_t)bid * 4096;
    unsigned short ep1b = f2b(ep1);
    int e = tid * 8;                         // exactly covers 4096
    us8 v = *(const us8*)(ag + e);
    int row = e >> 6, col = e & 63;
    int j = row - col;
    if (j >= 0 && j < 8) v[j] = ep1b;        // adj diag is 0 -> overwrite
    *(us8*)(ldsAdj + ((e << 1) ^ ((row & 7) << 4))) = v;
  }
  // ---- stage x row-major bf16 into ldsC (linear) ----
  if (FP32IN) {
    const float* xg = (const float*)xsrc + (size_t)bid * 8192;
    for (int e = tid * 4; e < 8192; e += 2048) {
      float4 v = *(const float4*)(xg + e);
      us4 h4; h4.x = f2b(v.x); h4.y = f2b(v.y); h4.z = f2b(v.z); h4.w = f2b(v.w);
      *(us4*)(ldsC + e * 2) = h4;
    }
  } else {
    const unsigned short* xg = (const unsigned short*)xsrc + (size_t)bid * 8192;
    for (int e = tid * 8; e < 8192; e += 4096)
      *(us8*)(ldsC + e * 2) = *(const us8*)(xg + e);
  }
  __syncthreads();

  // ---- transpose x_rm -> ldsB = x^T [128][64] swz ----
  {
    int d = tid & 127, mg = (tid >> 7) * 16;
    #pragma unroll
    for (int mb = 0; mb < 16; mb += 8) {
      us8 v;
      #pragma unroll
      for (int j = 0; j < 8; ++j)
        v[j] = *(const unsigned short*)(ldsC + ((mg + mb + j) << 8) + (d << 1));
      *(us8*)(ldsB + (((d << 7) + ((mg + mb) << 1)) ^ ((d & 7) << 4))) = v;
    }
  }
  __syncthreads();

  // ---- mm1: t = (adj+ep1*I) @ x ; tiles (rt, wv) -> ldsC swz (x_rm dead) ----
  {
    f32x4 acc[4] = {};
    #pragma unroll
    for (int rt = 0; rt < 4; ++rt) {
      #pragma unroll
      for (int k0 = 0; k0 < 64; k0 += 32) {
        bf16x8 a = frag(ldsAdj, rt * 16 + lr, 64, k0 + lkh * 8);
        bf16x8 b = frag(ldsB, wrow, 64, k0 + lkh * 8);
        acc[rt] = mm(a, b, acc[rt]);
      }
    }
    #pragma unroll
    for (int rt = 0; rt < 4; ++rt) {
      #pragma unroll
      for (int r = 0; r < 4; ++r) {
        int row = rt * 16 + lkh * 4 + r;
        *(unsigned short*)(ldsC + (((row << 8) + (wrow << 1)) ^ ((row & 7) << 4))) = f2b(acc[rt][r]);
      }
    }
  }
  __syncthreads();

  // ---- mm2: u = leaky(t @ W1 + b1) -> ldsB (x^T dead) ----
  #pragma unroll
  for (int rt = 0; rt < 4; ++rt) {
    f32x4 acc = {};
    #pragma unroll
    for (int kk = 0; kk < 4; ++kk) {
      bf16x8 a = frag(ldsC, rt * 16 + lr, 128, kk * 32 + lkh * 8);
      acc = mm(a, w1f[kk], acc);
    }
    #pragma unroll
    for (int r = 0; r < 4; ++r) {
      int row = rt * 16 + lkh * 4 + r;
      *(unsigned short*)(ldsB + (((row << 8) + (wrow << 1)) ^ ((row & 7) << 4))) = f2b(lk(acc[r] + bb1));
    }
  }
  __syncthreads();

  // ---- mm3: h = u @ W2 + b2, mask deleted row -> ldsC (t dead) ----
  #pragma unroll
  for (int rt = 0; rt < 4; ++rt) {
    f32x4 acc = {};
    #pragma unroll
    for (int kk = 0; kk < 4; ++kk) {
      bf16x8 a = frag(ldsB, rt * 16 + lr, 128, kk * 32 + lkh * 8);
      acc = mm(a, w2f[kk], acc);
    }
    #pragma unroll
    for (int r = 0; r < 4; ++r) {
      int row = rt * 16 + lkh * 4 + r;
      float v = acc[r] + bb2;
      if (row == del) v = 0.f;
      *(unsigned short*)(ldsC + (((row << 8) + (wrow << 1)) ^ ((row & 7) << 4))) = f2b(v);
    }
  }
  __syncthreads();

  // ---- global write h + BN per-feature partials ----
  size_t gbase = (size_t)bid * 8192;
  for (int e = tid * 8; e < 8192; e += 4096) {
    int m = e >> 7, d0 = e & 127;
    us8 v = *(const us8*)(ldsC + (((m << 8) + (d0 << 1)) ^ ((m & 7) << 4)));
    *(us8*)(hout + gbase + e) = v;
  }
  {
    int d = tid & 127, q = tid >> 7;
    float sm = 0.f, sq = 0.f;
    for (int m = q * 16; m < q * 16 + 16; ++m) {
      float v = b2f(*(const unsigned short*)(ldsC + (((m << 8) + (d << 1)) ^ ((m & 7) << 4))));
      sm += v; sq += v * v;
    }
    ldsR[tid] = sm; ldsR[512 + tid] = sq;
    __syncthreads();
    if (tid < 128) {
      psum[(size_t)bid * 128 + tid] = ldsR[tid] + ldsR[tid + 128] + ldsR[tid + 256] + ldsR[tid + 384];
      psq[(size_t)bid * 128 + tid]  = ldsR[512 + tid] + ldsR[640 + tid] + ldsR[768 + tid] + ldsR[896 + tid];
    }
  }
}

// BN stage-1 reduce, coalesced: block b sums rows b*64..+63 of p1s/p1q
__global__ __launch_bounds__(256) void k_bnred(const float* __restrict__ p1s,
    const float* __restrict__ p1q, float* __restrict__ q1s, float* __restrict__ q1q) {
  __shared__ float red[512];
  int b = blockIdx.x, tid = threadIdx.x;
  int d = tid & 127, jh = tid >> 7;
  float s = 0.f, q = 0.f;
  for (int j = b * 64 + jh; j < b * 64 + 64; j += 2) {
    s += p1s[(size_t)j * 128 + d];
    q += p1q[(size_t)j * 128 + d];
  }
  red[tid] = s; red[256 + tid] = q;
  __syncthreads();
  if (tid < 128) {
    q1s[(size_t)b * 128 + d] = red[d] + red[d + 128];
    q1q[(size_t)b * 128 + d] = red[256 + d] + red[384 + d];
  }
}

// Finalize BN for both branches into fused scale/shift (deterministic)
__global__ __launch_bounds__(128) void k_bnfin(const float* __restrict__ q1s,
    const float* __restrict__ q1q, const float* __restrict__ p2s,
    const float* __restrict__ p2q, const float* __restrict__ gam1,
    const float* __restrict__ bet1, const float* __restrict__ gam2,
    const float* __restrict__ bet2, float* __restrict__ bnA, float* __restrict__ bnB,
    float* __restrict__ bnsA, float* __restrict__ bnsB) {
  int d = threadIdx.x;
  float s = 0.f, q = 0.f, s2 = 0.f, q2 = 0.f;
  for (int j = 0; j < 64; ++j) {
    s  += q1s[j * 128 + d];  q  += q1q[j * 128 + d];
    s2 += p2s[j * 128 + d];  q2 += p2q[j * 128 + d];
  }
  const float cnt1 = 4096.0f * 63.0f;
  float mean = s / cnt1;
  float var = q / cnt1 - mean * mean;
  float A = gam1[d] * rsqrtf(var + 1e-5f);
  bnA[d] = A; bnB[d] = bet1[d] - mean * A;
  float mean2 = s2 / 4096.0f;
  float var2 = q2 / 4096.0f - mean2 * mean2;
  float A2 = gam2[d] * rsqrtf(var2 + 1e-5f);
  bnsA[d] = A2; bnsB[d] = bet2[d] - mean2 * A2;
}

// x_new = leaky( where(valid, BN1(h1), 0) + BN2(h2[g]) ); optional pool fusion
template<int WRITE_X, int DO_POOL>
__global__ __launch_bounds__(256) void k_combine(const unsigned short* __restrict__ h1,
    const unsigned short* __restrict__ h2, const float* __restrict__ bnA,
    const float* __restrict__ bnB, const float* __restrict__ bnsA,
    const float* __restrict__ bnsB, unsigned short* __restrict__ xo,
    float* __restrict__ pp) {
  __shared__ float A1[128], B1[128], A2[128], B2[128];
  __shared__ float pl[16][128];
  int tid = threadIdx.x;
  if (tid < 128) { A1[tid] = bnA[tid]; B1[tid] = bnB[tid]; A2[tid] = bnsA[tid]; B2[tid] = bnsB[tid]; }
  __syncthreads();
  int s = blockIdx.x, g = s >> 6, del = s & 63;
  size_t sb = (size_t)s * 8192, gb = (size_t)g * 8192;
  float ps[8] = {0.f, 0.f, 0.f, 0.f, 0.f, 0.f, 0.f, 0.f};
  for (int e = tid * 8; e < 8192; e += 2048) {
    int m = e >> 7, d0 = e & 127;
    us8 a = *(const us8*)(h1 + sb + e);
    us8 b = *(const us8*)(h2 + gb + e);
    us8 o;
    #pragma unroll
    for (int j = 0; j < 8; ++j) {
      int d = d0 + j;
      float hv = (m == del) ? 0.f : fmaf(b2f(a[j]), A1[d], B1[d]);
      float h2v = fmaf(b2f(b[j]), A2[d], B2[d]);
      float vv = lk(hv + h2v);
      o[j] = f2b(vv);
      if (DO_POOL) ps[j] += vv;
    }
    if (WRITE_X) *(us8*)(xo + sb + e) = o;
  }
  if (DO_POOL) {
    int rg = tid >> 4, c8 = (tid & 15) * 8;
    #pragma unroll
    for (int j = 0; j < 8; ++j) pl[rg][c8 + j] = ps[j];
    __syncthreads();
    if (tid < 128) {
      float s2 = 0.f;
      #pragma unroll
      for (int r = 0; r < 16; ++r) s2 += pl[r][tid];
      pp[(size_t)blockIdx.x * 128 + tid] = s2 * (1.0f / 63.0f);  // / num_nodes
    }
  }
}

// final readout MLP per graph, fp32 out
__global__ __launch_bounds__(256) void k_final(const float* __restrict__ pp,
    const float* __restrict__ W1, const float* __restrict__ b1,
    const float* __restrict__ W2, const float* __restrict__ b2,
    float* __restrict__ out) {
  __shared__ float hg[128];
  __shared__ float z[256];
  int g = blockIdx.x, t = threadIdx.x;
  if (t < 128) {
    float s = 0.f;
    for (int p = 0; p < 64; ++p) s += pp[(size_t)(g * 64 + p) * 128 + t];
    hg[t] = s * (1.0f / 64.0f);
  }
  __syncthreads();
  float a = b1[t];
  for (int d = 0; d < 128; ++d) a = fmaf(hg[d], W1[d * 256 + t], a);
  z[t] = lk(a);
  __syncthreads();
  if (t < 10) {
    float o = b2[t];
    for (int j = 0; j < 256; ++j) o = fmaf(z[j], W2[j * 10 + t], o);
    out[g * 10 + t] = o;
  }
}

extern "C" void kernel_launch(void* const* d_in, const int* in_sizes, int n_in,
                              void* d_out, int out_size, void* d_ws, size_t ws_size,
                              hipStream_t stream) {
  (void)in_sizes; (void)n_in; (void)out_size; (void)ws_size;
  const float* x    = (const float*)d_in[0];
  const float* adj  = (const float*)d_in[1];
  const float* oadj = (const float*)d_in[2];
  const float* gW1  = (const float*)d_in[3];
  const float* gb1  = (const float*)d_in[4];
  const float* gW2  = (const float*)d_in[5];
  const float* gb2  = (const float*)d_in[6];
  const float* geps = (const float*)d_in[7];
  const float* sW1  = (const float*)d_in[8];
  const float* sb1  = (const float*)d_in[9];
  const float* sW2  = (const float*)d_in[10];
  const float* sb2  = (const float*)d_in[11];
  const float* seps = (const float*)d_in[12];
  const float* bng  = (const float*)d_in[13];
  const float* bnb  = (const float*)d_in[14];
  const float* bnsg = (const float*)d_in[15];
  const float* bnsb = (const float*)d_in[16];
  const float* fW1  = (const float*)d_in[17];
  const float* fb1  = (const float*)d_in[18];
  const float* fW2  = (const float*)d_in[19];
  const float* fb2  = (const float*)d_in[20];
  float* out = (float*)d_out;

  char* w = (char*)d_ws;
  unsigned short* xw   = (unsigned short*)w; w += 67108864;   // x bf16 [4096][64][128]
  unsigned short* h1   = (unsigned short*)w; w += 67108864;   // h1 bf16
  unsigned short* adjb = (unsigned short*)w; w += 33554432;   // adj bf16 [4096][64][64]
  unsigned short* h2   = (unsigned short*)w; w += 1048576;    // h2 bf16 [64][64][128]
  unsigned short* oadjb= (unsigned short*)w; w += 524288;     // oadj bf16
  unsigned short* wt   = (unsigned short*)w; w += 524288;     // 16x bf16 [128][128] W^T
  float* xsum = (float*)w;          w += 2097152;             // fp32 [64][64][128]
  float* p1s  = (float*)w;          w += 2097152;
  float* p1q  = (float*)w;          w += 2097152;
  float* p2s  = (float*)w;          w += 32768;
  float* p2q  = (float*)w;          w += 32768;
  float* q1s  = (float*)w;          w += 32768;
  float* q1q  = (float*)w;          w += 32768;
  float* bnA  = (float*)w;          w += 512;
  float* bnB  = (float*)w;          w += 512;
  float* bnsA = (float*)w;          w += 512;
  float* bnsB = (float*)w;          w += 512;
  float* pp   = (float*)w;          w += 2097152;             // pool partials [4096][128]

  k_prep<<<16, 256, 0, stream>>>(gW1, gW2, sW1, sW2, wt);
  k_cast<<<32768, 256, 0, stream>>>(x, xw, 8388608);
  k_cast<<<16384, 256, 0, stream>>>(adj, adjb, 4194304);
  k_cast<<<256, 256, 0, stream>>>(oadj, oadjb, 65536);

  for (int i = 0; i < 4; ++i) {
    k_segmean<<<4096, 128, 0, stream>>>(xw, xsum);
    k_gin<false><<<4096, 512, 0, stream>>>(xw, adjb,
        wt + (i * 4 + 0) * 16384, wt + (i * 4 + 1) * 16384,
        gb1 + i * 128, gb2 + i * 128, geps + i, h1, p1s, p1q, 1);
    k_gin<true><<<64, 512, 0, stream>>>(xsum, oadjb,
        wt + (i * 4 + 2) * 16384, wt + (i * 4 + 3) * 16384,
        sb1 + i * 128, sb2 + i * 128, seps + i, h2, p2s, p2q, 0);
    k_bnred<<<64, 256, 0, stream>>>(p1s, p1q, q1s, q1q);
    k_bnfin<<<1, 128, 0, stream>>>(q1s, q1q, p2s, p2q, bng + i * 128,
        bnb + i * 128, bnsg + i * 128, bnsb + i * 128, bnA, bnB, bnsA, bnsB);
    if (i < 3) k_combine<1, 0><<<4096, 256, 0, stream>>>(h1, h2, bnA, bnB, bnsA, bnsB, xw, pp);
    else       k_combine<0, 1><<<4096, 256, 0, stream>>>(h1, h2, bnA, bnB, bnsA, bnsB, xw, pp);
  }
  k_final<<<64, 256, 0, stream>>>(pp, fW1, fb1, fW2, fb2, out);
}

// Round 5
// 567.644 us; speedup vs baseline: 1.7634x; 1.0254x over previous
//
#include <hip/hip_runtime.h>
#include <hip/hip_bf16.h>

// DenseDSSnetwork: 4-layer DSS-GIN over 4096 node-deleted subgraphs + graph branch.
// Inputs fp32, OUTPUT fp32 [64,10]. bf16 MFMA (16x16x32), fp32 accumulate.
// This round: bit-packed adjacency (0/1 -> 1 bit, expanded in LDS staging),
// segmean fused into combine (register-static per-graph partials), graph-branch
// GIN merged into the main 4160-block grid, x-cast fused with layer-0 segmean.

typedef __bf16 bf16x8 __attribute__((ext_vector_type(8)));
typedef float f32x4 __attribute__((ext_vector_type(4)));
typedef unsigned short us8 __attribute__((ext_vector_type(8)));
typedef unsigned short us4 __attribute__((ext_vector_type(4)));

__device__ __forceinline__ unsigned short f2b(float f) {
  unsigned u = __builtin_bit_cast(unsigned, f);
  u += 0x7FFFu + ((u >> 16) & 1u);            // RNE
  return (unsigned short)(u >> 16);
}
__device__ __forceinline__ float b2f(unsigned short h) {
  return __builtin_bit_cast(float, (unsigned)h << 16);
}
__device__ __forceinline__ f32x4 mm(bf16x8 a, bf16x8 b, f32x4 c) {
  return __builtin_amdgcn_mfma_f32_16x16x32_bf16(a, b, c, 0, 0, 0);
}
__device__ __forceinline__ bf16x8 frag(const char* base, int row, int Kelems, int k0) {
  int off = (row * Kelems + k0) * 2;
  off ^= (row & 7) << 4;
  return *(const bf16x8*)(base + off);
}
__device__ __forceinline__ float lk(float v) { return v > 0.f ? v : 0.01f * v; }

// Weight prep: W[k][n] fp32 -> Wt[n][k] bf16, 16 matrices
__global__ __launch_bounds__(256) void k_prep(const float* __restrict__ g1,
    const float* __restrict__ g2, const float* __restrict__ s1,
    const float* __restrict__ s2, unsigned short* __restrict__ wt) {
  int b = blockIdx.x;              // 0..15
  int l = b >> 2, j = b & 3;
  const float* src = (j == 0 ? g1 : j == 1 ? g2 : j == 2 ? s1 : s2) + l * 16384;
  unsigned short* dst = wt + b * 16384;
  for (int e = threadIdx.x; e < 16384; e += 256) {
    int n = e >> 7, k = e & 127;
    dst[e] = f2b(src[k * 128 + n]);
  }
}

// adj fp32 (0/1) -> 1 bit. Per graph: 64 rows x 64 bits = 256 u16.
__global__ __launch_bounds__(256) void k_pack(const float* __restrict__ src,
                                              unsigned short* __restrict__ dst) {
  int sub = blockIdx.x, t = threadIdx.x;
  const float* p = src + (size_t)sub * 4096 + (t >> 2) * 64 + (t & 3) * 16;
  unsigned bits = 0;
  #pragma unroll
  for (int j4 = 0; j4 < 4; ++j4) {
    float4 v = *(const float4*)(p + j4 * 4);
    bits |= (unsigned)(v.x != 0.f) << (j4 * 4);
    bits |= (unsigned)(v.y != 0.f) << (j4 * 4 + 1);
    bits |= (unsigned)(v.z != 0.f) << (j4 * 4 + 2);
    bits |= (unsigned)(v.w != 0.f) << (j4 * 4 + 3);
  }
  dst[(size_t)sub * 256 + t] = (unsigned short)bits;
}

// layer-0: cast x fp32->bf16 AND produce per-16-subgraph xsum partials.
// block b: subgraphs b*16..+16; thread t owns elems e = t*32..+32 (m = t/4 const).
__global__ __launch_bounds__(256) void k_castseg(const float* __restrict__ x,
    unsigned short* __restrict__ xw, float* __restrict__ pxs) {
  int b = blockIdx.x, t = threadIdx.x;
  int e0 = t * 32;
  float acc[32];
  #pragma unroll
  for (int j = 0; j < 32; ++j) acc[j] = 0.f;
  for (int ss = 0; ss < 16; ++ss) {
    size_t sb = ((size_t)b * 16 + ss) * 8192 + e0;
    const float* p = x + sb;
    unsigned short* q = xw + sb;
    #pragma unroll
    for (int c = 0; c < 8; ++c) {
      float4 v = *(const float4*)(p + c * 4);
      acc[c * 4 + 0] += v.x; acc[c * 4 + 1] += v.y;
      acc[c * 4 + 2] += v.z; acc[c * 4 + 3] += v.w;
      us4 h; h.x = f2b(v.x); h.y = f2b(v.y); h.z = f2b(v.z); h.w = f2b(v.w);
      *(us4*)(q + c * 4) = h;
    }
  }
  float* o = pxs + (size_t)b * 8192 + e0;
  #pragma unroll
  for (int c = 0; c < 8; ++c)
    *(float4*)(o + c * 4) = make_float4(acc[c * 4], acc[c * 4 + 1], acc[c * 4 + 2], acc[c * 4 + 3]);
}

// Fused GIN, merged grid: blocks 0..4095 = subgraph branch (gnn weights, mask),
// blocks 4096..4159 = graph branch (gs weights, x = sum of 4 pxs partials / 64).
// 512 threads = 8 waves; wave w owns output cols w*16..+15; W1/W2 in registers.
__global__ __launch_bounds__(512, 4) void k_gin(
    const unsigned short* __restrict__ xw, const float* __restrict__ pxs,
    const unsigned short* __restrict__ badj, const unsigned short* __restrict__ boadj,
    const unsigned short* __restrict__ W1g, const unsigned short* __restrict__ W2g,
    const unsigned short* __restrict__ W1s, const unsigned short* __restrict__ W2s,
    const float* __restrict__ b1g, const float* __restrict__ b2g,
    const float* __restrict__ b1s, const float* __restrict__ b2s,
    const float* __restrict__ epg, const float* __restrict__ epss,
    unsigned short* __restrict__ h1, unsigned short* __restrict__ h2,
    float* __restrict__ p1s, float* __restrict__ p1q,
    float* __restrict__ p2s, float* __restrict__ p2q) {
  __shared__ __align__(16) char lds[40960];
  char* ldsAdj = lds;              // 8KB : bf16 [64][64] swz (adj + ep1*I)
  char* ldsB   = lds + 8192;       // 16KB: x^T [128][64] swz, then u [64][128] swz
  char* ldsC   = lds + 24576;      // 16KB: x_rm [64][128] linear, then t, then h (swz)
  float* ldsR  = (float*)lds;      // reduce scratch (overlaps ldsAdj, dead by then)

  const int tid = threadIdx.x;
  const int bid = blockIdx.x;
  const bool SUB = bid < 4096;
  const int lb = SUB ? bid : bid - 4096;
  const int wv = tid >> 6, ln = tid & 63;
  const int lr = ln & 15, lkh = ln >> 4;
  const int wrow = wv * 16 + lr;   // this lane's output column
  const float ep1 = 1.0f + (SUB ? epg[0] : epss[0]);
  const int del = SUB ? (bid & 63) : -1;
  const unsigned short* W1t = SUB ? W1g : W1s;
  const unsigned short* W2t = SUB ? W2g : W2s;

  // ---- W fragments into registers (one-time, hidden behind staging) ----
  bf16x8 w1f[4], w2f[4];
  #pragma unroll
  for (int kk = 0; kk < 4; ++kk) {
    w1f[kk] = *(const bf16x8*)(W1t + (size_t)wrow * 128 + kk * 32 + lkh * 8);
    w2f[kk] = *(const bf16x8*)(W2t + (size_t)wrow * 128 + kk * 32 + lkh * 8);
  }
  const float bb1 = (SUB ? b1g : b1s)[wrow];
  const float bb2 = (SUB ? b2g : b2s)[wrow];

  // ---- stage adj from bit-pack (+ep1 on diagonal) ----
  {
    const unsigned char* bits =
        (const unsigned char*)(SUB ? badj + (size_t)lb * 256 : boadj + (size_t)lb * 256);
    unsigned char bb = bits[tid];            // 512 bytes per graph
    int row = tid >> 3, o = tid & 7;
    unsigned short ep1b = f2b(ep1);
    us8 v;
    #pragma unroll
    for (int j = 0; j < 8; ++j) v[j] = ((bb >> j) & 1) ? (unsigned short)0x3F80 : (unsigned short)0;
    int j0 = row - o * 8;
    if (j0 >= 0 && j0 < 8) v[j0] = ep1b;     // diag of adj is 0 -> overwrite
    int e = tid * 8;
    *(us8*)(ldsAdj + ((e << 1) ^ ((row & 7) << 4))) = v;
  }
  // ---- stage x row-major bf16 into ldsC (linear) ----
  if (SUB) {
    const unsigned short* xg = xw + (size_t)bid * 8192;
    for (int e = tid * 8; e < 8192; e += 4096)
      *(us8*)(ldsC + e * 2) = *(const us8*)(xg + e);
  } else {
    const float* p = pxs + (size_t)lb * 4 * 8192;
    int e0 = tid * 16;
    #pragma unroll
    for (int c = 0; c < 4; ++c) {
      float4 s = {0.f, 0.f, 0.f, 0.f};
      #pragma unroll
      for (int qt = 0; qt < 4; ++qt) {
        float4 v = *(const float4*)(p + qt * 8192 + e0 + c * 4);
        s.x += v.x; s.y += v.y; s.z += v.z; s.w += v.w;
      }
      us4 h; h.x = f2b(s.x * 0.015625f); h.y = f2b(s.y * 0.015625f);
      h.z = f2b(s.z * 0.015625f); h.w = f2b(s.w * 0.015625f);
      *(us4*)(ldsC + (e0 + c * 4) * 2) = h;
    }
  }
  __syncthreads();

  // ---- transpose x_rm -> ldsB = x^T [128][64] swz ----
  {
    int d = tid & 127, mg = (tid >> 7) * 16;
    #pragma unroll
    for (int mb = 0; mb < 16; mb += 8) {
      us8 v;
      #pragma unroll
      for (int j = 0; j < 8; ++j)
        v[j] = *(const unsigned short*)(ldsC + ((mg + mb + j) << 8) + (d << 1));
      *(us8*)(ldsB + (((d << 7) + ((mg + mb) << 1)) ^ ((d & 7) << 4))) = v;
    }
  }
  __syncthreads();

  // ---- mm1: t = (adj+ep1*I) @ x -> ldsC swz (x_rm dead) ----
  {
    f32x4 acc[4] = {};
    #pragma unroll
    for (int rt = 0; rt < 4; ++rt) {
      #pragma unroll
      for (int k0 = 0; k0 < 64; k0 += 32) {
        bf16x8 a = frag(ldsAdj, rt * 16 + lr, 64, k0 + lkh * 8);
        bf16x8 b = frag(ldsB, wrow, 64, k0 + lkh * 8);
        acc[rt] = mm(a, b, acc[rt]);
      }
    }
    #pragma unroll
    for (int rt = 0; rt < 4; ++rt) {
      #pragma unroll
      for (int r = 0; r < 4; ++r) {
        int row = rt * 16 + lkh * 4 + r;
        *(unsigned short*)(ldsC + (((row << 8) + (wrow << 1)) ^ ((row & 7) << 4))) = f2b(acc[rt][r]);
      }
    }
  }
  __syncthreads();

  // ---- mm2: u = leaky(t @ W1 + b1) -> ldsB (x^T dead) ----
  #pragma unroll
  for (int rt = 0; rt < 4; ++rt) {
    f32x4 acc = {};
    #pragma unroll
    for (int kk = 0; kk < 4; ++kk) {
      bf16x8 a = frag(ldsC, rt * 16 + lr, 128, kk * 32 + lkh * 8);
      acc = mm(a, w1f[kk], acc);
    }
    #pragma unroll
    for (int r = 0; r < 4; ++r) {
      int row = rt * 16 + lkh * 4 + r;
      *(unsigned short*)(ldsB + (((row << 8) + (wrow << 1)) ^ ((row & 7) << 4))) = f2b(lk(acc[r] + bb1));
    }
  }
  __syncthreads();

  // ---- mm3: h = u @ W2 + b2, mask deleted row -> ldsC (t dead) ----
  #pragma unroll
  for (int rt = 0; rt < 4; ++rt) {
    f32x4 acc = {};
    #pragma unroll
    for (int kk = 0; kk < 4; ++kk) {
      bf16x8 a = frag(ldsB, rt * 16 + lr, 128, kk * 32 + lkh * 8);
      acc = mm(a, w2f[kk], acc);
    }
    #pragma unroll
    for (int r = 0; r < 4; ++r) {
      int row = rt * 16 + lkh * 4 + r;
      float v = acc[r] + bb2;
      if (row == del) v = 0.f;
      *(unsigned short*)(ldsC + (((row << 8) + (wrow << 1)) ^ ((row & 7) << 4))) = f2b(v);
    }
  }
  __syncthreads();

  // ---- global write h + BN per-feature partials ----
  unsigned short* hout = SUB ? h1 + (size_t)bid * 8192 : h2 + (size_t)lb * 8192;
  for (int e = tid * 8; e < 8192; e += 4096) {
    int m = e >> 7, d0 = e & 127;
    us8 v = *(const us8*)(ldsC + (((m << 8) + (d0 << 1)) ^ ((m & 7) << 4)));
    *(us8*)(hout + e) = v;
  }
  {
    int d = tid & 127, q = tid >> 7;
    float sm = 0.f, sq = 0.f;
    for (int m = q * 16; m < q * 16 + 16; ++m) {
      float v = b2f(*(const unsigned short*)(ldsC + (((m << 8) + (d << 1)) ^ ((m & 7) << 4))));
      sm += v; sq += v * v;
    }
    ldsR[tid] = sm; ldsR[512 + tid] = sq;
    __syncthreads();
    if (tid < 128) {
      float* ps = SUB ? p1s + (size_t)bid * 128 : p2s + (size_t)lb * 128;
      float* pq = SUB ? p1q + (size_t)bid * 128 : p2q + (size_t)lb * 128;
      ps[tid] = ldsR[tid] + ldsR[tid + 128] + ldsR[tid + 256] + ldsR[tid + 384];
      pq[tid] = ldsR[512 + tid] + ldsR[640 + tid] + ldsR[768 + tid] + ldsR[896 + tid];
    }
  }
}

// BN stage-1 reduce, coalesced: block b sums rows b*64..+63 of p1s/p1q
__global__ __launch_bounds__(256) void k_bnred(const float* __restrict__ p1s,
    const float* __restrict__ p1q, float* __restrict__ q1s, float* __restrict__ q1q) {
  __shared__ float red[512];
  int b = blockIdx.x, tid = threadIdx.x;
  int d = tid & 127, jh = tid >> 7;
  float s = 0.f, q = 0.f;
  for (int j = b * 64 + jh; j < b * 64 + 64; j += 2) {
    s += p1s[(size_t)j * 128 + d];
    q += p1q[(size_t)j * 128 + d];
  }
  red[tid] = s; red[256 + tid] = q;
  __syncthreads();
  if (tid < 128) {
    q1s[(size_t)b * 128 + d] = red[d] + red[d + 128];
    q1q[(size_t)b * 128 + d] = red[256 + d] + red[384 + d];
  }
}

// Finalize BN for both branches into fused scale/shift (deterministic)
__global__ __launch_bounds__(128) void k_bnfin(const float* __restrict__ q1s,
    const float* __restrict__ q1q, const float* __restrict__ p2s,
    const float* __restrict__ p2q, const float* __restrict__ gam1,
    const float* __restrict__ bet1, const float* __restrict__ gam2,
    const float* __restrict__ bet2, float* __restrict__ bnA, float* __restrict__ bnB,
    float* __restrict__ bnsA, float* __restrict__ bnsB) {
  int d = threadIdx.x;
  float s = 0.f, q = 0.f, s2 = 0.f, q2 = 0.f;
  for (int j = 0; j < 64; ++j) {
    s  += q1s[j * 128 + d];  q  += q1q[j * 128 + d];
    s2 += p2s[j * 128 + d];  q2 += p2q[j * 128 + d];
  }
  const float cnt1 = 4096.0f * 63.0f;
  float mean = s / cnt1;
  float var = q / cnt1 - mean * mean;
  float A = gam1[d] * rsqrtf(var + 1e-5f);
  bnA[d] = A; bnB[d] = bet1[d] - mean * A;
  float mean2 = s2 / 4096.0f;
  float var2 = q2 / 4096.0f - mean2 * mean2;
  float A2 = gam2[d] * rsqrtf(var2 + 1e-5f);
  bnsA[d] = A2; bnsB[d] = bet2[d] - mean2 * A2;
}

// x_new = leaky( where(valid, BN1(h1), 0) + BN2(h2[g]) ), fused with segmean
// (per-16-subgraph xsum partials) or, at the last layer, graph-pool partials.
// block b: graph g=b>>2, subgraphs b*16..+16; thread t owns e=t*32..+32 (m=t/4).
template<int LAST>
__global__ __launch_bounds__(256) void k_combine2(const unsigned short* __restrict__ h1,
    const unsigned short* __restrict__ h2, const float* __restrict__ bnA,
    const float* __restrict__ bnB, const float* __restrict__ bnsA,
    const float* __restrict__ bnsB, unsigned short* __restrict__ xo,
    float* __restrict__ pxs, float* __restrict__ ppool) {
  __shared__ float A1[128], B1[128];
  __shared__ float sh2[8192];      // BN2-applied h2 for this graph (32KB)
  int tid = threadIdx.x;
  int b = blockIdx.x, g = b >> 2;
  if (tid < 128) { A1[tid] = bnA[tid]; B1[tid] = bnB[tid]; }
  {
    int e0 = tid * 32;
    const unsigned short* hb = h2 + (size_t)g * 8192 + e0;
    #pragma unroll
    for (int c = 0; c < 4; ++c) {
      us8 v = *(const us8*)(hb + c * 8);
      #pragma unroll
      for (int j = 0; j < 8; ++j) {
        int d = (e0 + c * 8 + j) & 127;
        sh2[e0 + c * 8 + j] = fmaf(b2f(v[j]), bnsA[d], bnsB[d]);
      }
    }
  }
  __syncthreads();

  int e0 = tid * 32;
  int m = tid >> 2;                // constant per thread
  float acc[32];
  #pragma unroll
  for (int j = 0; j < 32; ++j) acc[j] = 0.f;

  for (int ss = 0; ss < 16; ++ss) {
    int s = b * 16 + ss;
    int del = s & 63;
    bool valid = (m != del);
    size_t sb = (size_t)s * 8192 + e0;
    const unsigned short* ha = h1 + sb;
    unsigned short* q = xo + sb;
    #pragma unroll
    for (int c = 0; c < 4; ++c) {
      us8 a = *(const us8*)(ha + c * 8);
      us8 o;
      #pragma unroll
      for (int j = 0; j < 8; ++j) {
        int e = e0 + c * 8 + j;
        int d = e & 127;
        float hv = valid ? fmaf(b2f(a[j]), A1[d], B1[d]) : 0.f;
        float vv = lk(hv + sh2[e]);
        o[j] = f2b(vv);
        acc[c * 8 + j] += vv;
      }
      if (!LAST) *(us8*)(q + c * 8) = o;
    }
  }
  if (!LAST) {
    float* o = pxs + (size_t)b * 8192 + e0;
    #pragma unroll
    for (int c = 0; c < 8; ++c)
      *(float4*)(o + c * 4) = make_float4(acc[c * 4], acc[c * 4 + 1], acc[c * 4 + 2], acc[c * 4 + 3]);
  } else {
    // pool partial: sum over m of acc, /63
    __syncthreads();               // done reading sh2 -> reuse as pl[8192]
    #pragma unroll
    for (int j = 0; j < 32; ++j) sh2[e0 + j] = acc[j];
    __syncthreads();
    if (tid < 128) {
      float s2 = 0.f;
      for (int mm2 = 0; mm2 < 64; ++mm2) s2 += sh2[mm2 * 128 + tid];
      ppool[(size_t)b * 128 + tid] = s2 * (1.0f / 63.0f);
    }
  }
}

// final readout MLP per graph, fp32 out
__global__ __launch_bounds__(256) void k_final(const float* __restrict__ ppool,
    const float* __restrict__ W1, const float* __restrict__ b1,
    const float* __restrict__ W2, const float* __restrict__ b2,
    float* __restrict__ out) {
  __shared__ float hg[128];
  __shared__ float z[256];
  int g = blockIdx.x, t = threadIdx.x;
  if (t < 128) {
    float s = ppool[(size_t)(g * 4 + 0) * 128 + t] + ppool[(size_t)(g * 4 + 1) * 128 + t]
            + ppool[(size_t)(g * 4 + 2) * 128 + t] + ppool[(size_t)(g * 4 + 3) * 128 + t];
    hg[t] = s * (1.0f / 64.0f);
  }
  __syncthreads();
  float a = b1[t];
  for (int d = 0; d < 128; ++d) a = fmaf(hg[d], W1[d * 256 + t], a);
  z[t] = lk(a);
  __syncthreads();
  if (t < 10) {
    float o = b2[t];
    for (int j = 0; j < 256; ++j) o = fmaf(z[j], W2[j * 10 + t], o);
    out[g * 10 + t] = o;
  }
}

extern "C" void kernel_launch(void* const* d_in, const int* in_sizes, int n_in,
                              void* d_out, int out_size, void* d_ws, size_t ws_size,
                              hipStream_t stream) {
  (void)in_sizes; (void)n_in; (void)out_size; (void)ws_size;
  const float* x    = (const float*)d_in[0];
  const float* adj  = (const float*)d_in[1];
  const float* oadj = (const float*)d_in[2];
  const float* gW1  = (const float*)d_in[3];
  const float* gb1  = (const float*)d_in[4];
  const float* gW2  = (const float*)d_in[5];
  const float* gb2  = (const float*)d_in[6];
  const float* geps = (const float*)d_in[7];
  const float* sW1  = (const float*)d_in[8];
  const float* sb1  = (const float*)d_in[9];
  const float* sW2  = (const float*)d_in[10];
  const float* sb2  = (const float*)d_in[11];
  const float* seps = (const float*)d_in[12];
  const float* bng  = (const float*)d_in[13];
  const float* bnb  = (const float*)d_in[14];
  const float* bnsg = (const float*)d_in[15];
  const float* bnsb = (const float*)d_in[16];
  const float* fW1  = (const float*)d_in[17];
  const float* fb1  = (const float*)d_in[18];
  const float* fW2  = (const float*)d_in[19];
  const float* fb2  = (const float*)d_in[20];
  float* out = (float*)d_out;

  char* w = (char*)d_ws;
  unsigned short* xw   = (unsigned short*)w; w += 67108864;   // x bf16 [4096][64][128]
  unsigned short* h1   = (unsigned short*)w; w += 67108864;   // h1 bf16
  unsigned short* h2   = (unsigned short*)w; w += 1048576;    // h2 bf16 [64][64][128]
  unsigned short* badj = (unsigned short*)w; w += 2097152;    // adj bits [4096][256]u16
  unsigned short* boadj= (unsigned short*)w; w += 32768;      // oadj bits [64][256]u16
  unsigned short* wt   = (unsigned short*)w; w += 524288;     // 16x bf16 [128][128] W^T
  float* pxs  = (float*)w;          w += 8388608;             // xsum partials [256][8192]
  float* p1s  = (float*)w;          w += 2097152;
  float* p1q  = (float*)w;          w += 2097152;
  float* p2s  = (float*)w;          w += 32768;
  float* p2q  = (float*)w;          w += 32768;
  float* q1s  = (float*)w;          w += 32768;
  float* q1q  = (float*)w;          w += 32768;
  float* bnA  = (float*)w;          w += 512;
  float* bnB  = (float*)w;          w += 512;
  float* bnsA = (float*)w;          w += 512;
  float* bnsB = (float*)w;          w += 512;
  float* ppool= (float*)w;          w += 131072;              // pool partials [256][128]

  k_prep<<<16, 256, 0, stream>>>(gW1, gW2, sW1, sW2, wt);
  k_pack<<<4096, 256, 0, stream>>>(adj, badj);
  k_pack<<<64, 256, 0, stream>>>(oadj, boadj);
  k_castseg<<<256, 256, 0, stream>>>(x, xw, pxs);

  for (int i = 0; i < 4; ++i) {
    k_gin<<<4160, 512, 0, stream>>>(xw, pxs, badj, boadj,
        wt + (i * 4 + 0) * 16384, wt + (i * 4 + 1) * 16384,
        wt + (i * 4 + 2) * 16384, wt + (i * 4 + 3) * 16384,
        gb1 + i * 128, gb2 + i * 128, sb1 + i * 128, sb2 + i * 128,
        geps + i, seps + i, h1, h2, p1s, p1q, p2s, p2q);
    k_bnred<<<64, 256, 0, stream>>>(p1s, p1q, q1s, q1q);
    k_bnfin<<<1, 128, 0, stream>>>(q1s, q1q, p2s, p2q, bng + i * 128,
        bnb + i * 128, bnsg + i * 128, bnsb + i * 128, bnA, bnB, bnsA, bnsB);
    if (i < 3) k_combine2<0><<<256, 256, 0, stream>>>(h1, h2, bnA, bnB, bnsA, bnsB, xw, pxs, ppool);
    else       k_combine2<1><<<256, 256, 0, stream>>>(h1, h2, bnA, bnB, bnsA, bnsB, xw, pxs, ppool);
  }
  k_final<<<64, 256, 0, stream>>>(ppool, fW1, fb1, fW2, fb2, out);
}

// Round 6
// 527.935 us; speedup vs baseline: 1.8961x; 1.0752x over previous
//
#include <hip/hip_runtime.h>
#include <hip/hip_bf16.h>

// DenseDSSnetwork: 4-layer DSS-GIN over 4096 node-deleted subgraphs + graph branch.
// Inputs fp32, OUTPUT fp32 [64,10]. bf16 MFMA (16x16x32), fp32 accumulate.
// Round 6: xw eliminated (gin recomputes x from h1/h2/BN in staging); combine2
// replaced by lean 1024-block k_xpart (segmean/pool partials only); castseg
// parallelized to 1024 blocks; h2 ping-pong, h1 in-place.

typedef __bf16 bf16x8 __attribute__((ext_vector_type(8)));
typedef float f32x4 __attribute__((ext_vector_type(4)));
typedef unsigned short us8 __attribute__((ext_vector_type(8)));
typedef unsigned short us4 __attribute__((ext_vector_type(4)));

__device__ __forceinline__ unsigned short f2b(float f) {
  unsigned u = __builtin_bit_cast(unsigned, f);
  u += 0x7FFFu + ((u >> 16) & 1u);            // RNE
  return (unsigned short)(u >> 16);
}
__device__ __forceinline__ float b2f(unsigned short h) {
  return __builtin_bit_cast(float, (unsigned)h << 16);
}
__device__ __forceinline__ f32x4 mm(bf16x8 a, bf16x8 b, f32x4 c) {
  return __builtin_amdgcn_mfma_f32_16x16x32_bf16(a, b, c, 0, 0, 0);
}
__device__ __forceinline__ bf16x8 frag(const char* base, int row, int Kelems, int k0) {
  int off = (row * Kelems + k0) * 2;
  off ^= (row & 7) << 4;
  return *(const bf16x8*)(base + off);
}
__device__ __forceinline__ float lk(float v) { return v > 0.f ? v : 0.01f * v; }

// Weight prep: W[k][n] fp32 -> Wt[n][k] bf16, 16 matrices
__global__ __launch_bounds__(256) void k_prep(const float* __restrict__ g1,
    const float* __restrict__ g2, const float* __restrict__ s1,
    const float* __restrict__ s2, unsigned short* __restrict__ wt) {
  int b = blockIdx.x;              // 0..15
  int l = b >> 2, j = b & 3;
  const float* src = (j == 0 ? g1 : j == 1 ? g2 : j == 2 ? s1 : s2) + l * 16384;
  unsigned short* dst = wt + b * 16384;
  for (int e = threadIdx.x; e < 16384; e += 256) {
    int n = e >> 7, k = e & 127;
    dst[e] = f2b(src[k * 128 + n]);
  }
}

// adj fp32 (0/1) -> 1 bit. Per graph: 64 rows x 64 bits = 256 u16.
__global__ __launch_bounds__(256) void k_pack(const float* __restrict__ src,
                                              unsigned short* __restrict__ dst) {
  int sub = blockIdx.x, t = threadIdx.x;
  const float* p = src + (size_t)sub * 4096 + (t >> 2) * 64 + (t & 3) * 16;
  unsigned bits = 0;
  #pragma unroll
  for (int j4 = 0; j4 < 4; ++j4) {
    float4 v = *(const float4*)(p + j4 * 4);
    bits |= (unsigned)(v.x != 0.f) << (j4 * 4);
    bits |= (unsigned)(v.y != 0.f) << (j4 * 4 + 1);
    bits |= (unsigned)(v.z != 0.f) << (j4 * 4 + 2);
    bits |= (unsigned)(v.w != 0.f) << (j4 * 4 + 3);
  }
  dst[(size_t)sub * 256 + t] = (unsigned short)bits;
}

// layer-0: cast x fp32->bf16 AND produce xsum partials.
// block b2: group bb=b2>>2 (subgraphs bb*16..+16), slice c=b2&3 (elems c*2048..+2048)
__global__ __launch_bounds__(256) void k_castseg(const float* __restrict__ x,
    unsigned short* __restrict__ xw, float* __restrict__ pxs) {
  int b2 = blockIdx.x, bb = b2 >> 2, c = b2 & 3, t = threadIdx.x;
  int e0 = c * 2048 + t * 8;
  float acc[8];
  #pragma unroll
  for (int j = 0; j < 8; ++j) acc[j] = 0.f;
  for (int ss = 0; ss < 16; ++ss) {
    size_t sb = ((size_t)bb * 16 + ss) * 8192 + e0;
    float4 v0 = *(const float4*)(x + sb);
    float4 v1 = *(const float4*)(x + sb + 4);
    acc[0] += v0.x; acc[1] += v0.y; acc[2] += v0.z; acc[3] += v0.w;
    acc[4] += v1.x; acc[5] += v1.y; acc[6] += v1.z; acc[7] += v1.w;
    us8 h;
    h[0] = f2b(v0.x); h[1] = f2b(v0.y); h[2] = f2b(v0.z); h[3] = f2b(v0.w);
    h[4] = f2b(v1.x); h[5] = f2b(v1.y); h[6] = f2b(v1.z); h[7] = f2b(v1.w);
    *(us8*)(xw + sb) = h;
  }
  float* o = pxs + (size_t)bb * 8192 + e0;
  *(float4*)o = make_float4(acc[0], acc[1], acc[2], acc[3]);
  *(float4*)(o + 4) = make_float4(acc[4], acc[5], acc[6], acc[7]);
}

// x recompute + segmean partials (or pool partials at LAST).
// block b2: bb=b2>>2 (16 subgraphs), c=b2&3 (2048-elem slice); graph g=bb>>2.
template<int LAST>
__global__ __launch_bounds__(256) void k_xpart(const unsigned short* __restrict__ h1,
    const unsigned short* __restrict__ h2prev, const float* __restrict__ bnA,
    const float* __restrict__ bnB, const float* __restrict__ bnsA,
    const float* __restrict__ bnsB, float* __restrict__ pxs,
    float* __restrict__ ppool) {
  __shared__ float sh2[2048];
  __shared__ float sA1[128], sB1[128];
  int b2 = blockIdx.x, bb = b2 >> 2, c = b2 & 3, g = bb >> 2;
  int t = threadIdx.x;
  int e0 = c * 2048 + t * 8;       // elem within [8192]
  int d0 = e0 & 127;
  int m = e0 >> 7;                 // node row, const per thread
  if (t < 128) { sA1[t] = bnA[t]; sB1[t] = bnB[t]; }
  {
    us8 v = *(const us8*)(h2prev + (size_t)g * 8192 + e0);
    float4 A2a = *(const float4*)(bnsA + d0), A2b = *(const float4*)(bnsA + d0 + 4);
    float4 B2a = *(const float4*)(bnsB + d0), B2b = *(const float4*)(bnsB + d0 + 4);
    float A2v[8], B2v[8];
    *(float4*)A2v = A2a; *(float4*)(A2v + 4) = A2b;
    *(float4*)B2v = B2a; *(float4*)(B2v + 4) = B2b;
    #pragma unroll
    for (int j = 0; j < 8; ++j) sh2[t * 8 + j] = fmaf(b2f(v[j]), A2v[j], B2v[j]);
  }
  __syncthreads();
  float acc[8];
  #pragma unroll
  for (int j = 0; j < 8; ++j) acc[j] = 0.f;
  for (int ss = 0; ss < 16; ++ss) {
    int s = bb * 16 + ss;
    bool valid = (m != (s & 63));
    us8 a = *(const us8*)(h1 + (size_t)s * 8192 + e0);
    #pragma unroll
    for (int j = 0; j < 8; ++j) {
      float hv = valid ? fmaf(b2f(a[j]), sA1[d0 + j], sB1[d0 + j]) : 0.f;
      acc[j] += lk(hv + sh2[t * 8 + j]);
    }
  }
  if (!LAST) {
    float* o = pxs + (size_t)bb * 8192 + e0;
    *(float4*)o = make_float4(acc[0], acc[1], acc[2], acc[3]);
    *(float4*)(o + 4) = make_float4(acc[4], acc[5], acc[6], acc[7]);
  } else {
    __syncthreads();               // done with sh2 -> reuse as reduce scratch
    #pragma unroll
    for (int j = 0; j < 8; ++j) sh2[t * 8 + j] = acc[j];
    __syncthreads();
    if (t < 128) {
      float s2 = 0.f;
      #pragma unroll
      for (int ml = 0; ml < 16; ++ml) s2 += sh2[ml * 128 + t];
      ppool[(size_t)b2 * 128 + t] = s2;   // raw sum; /4032 in k_final
    }
  }
}

// Fused GIN, merged grid: blocks 0..4095 subgraph branch, 4096..4159 graph branch.
// !FIRST: staging recomputes x = leaky(BN1(h1)+BN2(h2prev[g])) from h1 in place.
template<int FIRST>
__global__ __launch_bounds__(512, 4) void k_gin(
    const unsigned short* __restrict__ xw, unsigned short* __restrict__ h1,
    const unsigned short* __restrict__ h2prev, unsigned short* __restrict__ h2out,
    const float* __restrict__ pxs,
    const unsigned short* __restrict__ badj, const unsigned short* __restrict__ boadj,
    const unsigned short* __restrict__ W1g, const unsigned short* __restrict__ W2g,
    const unsigned short* __restrict__ W1s, const unsigned short* __restrict__ W2s,
    const float* __restrict__ b1g, const float* __restrict__ b2g,
    const float* __restrict__ b1s, const float* __restrict__ b2s,
    const float* __restrict__ epg, const float* __restrict__ epss,
    const float* __restrict__ bnA, const float* __restrict__ bnB,
    const float* __restrict__ bnsA, const float* __restrict__ bnsB,
    float* __restrict__ p1s, float* __restrict__ p1q,
    float* __restrict__ p2s, float* __restrict__ p2q) {
  __shared__ __align__(16) char lds[40960];
  char* ldsAdj = lds;              // 8KB : bf16 [64][64] swz (adj + ep1*I)
  char* ldsB   = lds + 8192;       // 16KB: x^T [128][64] swz, then u [64][128] swz
  char* ldsC   = lds + 24576;      // 16KB: x_rm [64][128] linear, then t, then h (swz)
  float* ldsR  = (float*)lds;      // reduce scratch (overlaps ldsAdj, dead by then)

  const int tid = threadIdx.x;
  const int bid = blockIdx.x;
  const bool SUB = bid < 4096;
  const int lb = SUB ? bid : bid - 4096;
  const int wv = tid >> 6, ln = tid & 63;
  const int lr = ln & 15, lkh = ln >> 4;
  const int wrow = wv * 16 + lr;
  const float ep1 = 1.0f + (SUB ? epg[0] : epss[0]);
  const int del = SUB ? (bid & 63) : -1;
  const unsigned short* W1t = SUB ? W1g : W1s;
  const unsigned short* W2t = SUB ? W2g : W2s;

  // ---- W fragments into registers ----
  bf16x8 w1f[4], w2f[4];
  #pragma unroll
  for (int kk = 0; kk < 4; ++kk) {
    w1f[kk] = *(const bf16x8*)(W1t + (size_t)wrow * 128 + kk * 32 + lkh * 8);
    w2f[kk] = *(const bf16x8*)(W2t + (size_t)wrow * 128 + kk * 32 + lkh * 8);
  }
  const float bb1 = (SUB ? b1g : b1s)[wrow];
  const float bb2 = (SUB ? b2g : b2s)[wrow];

  // ---- stage adj from bit-pack (+ep1 on diagonal) ----
  {
    const unsigned char* bits =
        (const unsigned char*)(SUB ? badj + (size_t)lb * 256 : boadj + (size_t)lb * 256);
    unsigned char bbt = bits[tid];
    int row = tid >> 3, o = tid & 7;
    unsigned short ep1b = f2b(ep1);
    us8 v;
    #pragma unroll
    for (int j = 0; j < 8; ++j) v[j] = ((bbt >> j) & 1) ? (unsigned short)0x3F80 : (unsigned short)0;
    int j0 = row - o * 8;
    if (j0 >= 0 && j0 < 8) v[j0] = ep1b;
    int e = tid * 8;
    *(us8*)(ldsAdj + ((e << 1) ^ ((row & 7) << 4))) = v;
  }
  // ---- stage x row-major bf16 into ldsC (linear) ----
  if (SUB) {
    if (FIRST) {
      const unsigned short* xg = xw + (size_t)bid * 8192;
      for (int e = tid * 8; e < 8192; e += 4096)
        *(us8*)(ldsC + e * 2) = *(const us8*)(xg + e);
    } else {
      const unsigned short* h1g = h1 + (size_t)bid * 8192;
      const unsigned short* h2g = h2prev + (size_t)(bid >> 6) * 8192;
      int e0 = tid * 16;
      int mrow = e0 >> 7;
      bool valid = (mrow != del);
      #pragma unroll
      for (int cc = 0; cc < 2; ++cc) {
        int e = e0 + cc * 8, d0 = e & 127;
        us8 a = *(const us8*)(h1g + e);
        us8 hb = *(const us8*)(h2g + e);
        float A1v[8], B1v[8], A2v[8], B2v[8];
        *(float4*)A1v = *(const float4*)(bnA + d0);  *(float4*)(A1v+4) = *(const float4*)(bnA + d0 + 4);
        *(float4*)B1v = *(const float4*)(bnB + d0);  *(float4*)(B1v+4) = *(const float4*)(bnB + d0 + 4);
        *(float4*)A2v = *(const float4*)(bnsA + d0); *(float4*)(A2v+4) = *(const float4*)(bnsA + d0 + 4);
        *(float4*)B2v = *(const float4*)(bnsB + d0); *(float4*)(B2v+4) = *(const float4*)(bnsB + d0 + 4);
        us8 o;
        #pragma unroll
        for (int j = 0; j < 8; ++j) {
          float hv = valid ? fmaf(b2f(a[j]), A1v[j], B1v[j]) : 0.f;
          float xv = lk(hv + fmaf(b2f(hb[j]), A2v[j], B2v[j]));
          o[j] = f2b(xv);
        }
        *(us8*)(ldsC + (e << 1)) = o;
      }
    }
  } else {
    const float* p = pxs + (size_t)lb * 4 * 8192;
    int e0 = tid * 16;
    #pragma unroll
    for (int cc = 0; cc < 4; ++cc) {
      float4 s = {0.f, 0.f, 0.f, 0.f};
      #pragma unroll
      for (int qt = 0; qt < 4; ++qt) {
        float4 v = *(const float4*)(p + qt * 8192 + e0 + cc * 4);
        s.x += v.x; s.y += v.y; s.z += v.z; s.w += v.w;
      }
      us4 h; h.x = f2b(s.x * 0.015625f); h.y = f2b(s.y * 0.015625f);
      h.z = f2b(s.z * 0.015625f); h.w = f2b(s.w * 0.015625f);
      *(us4*)(ldsC + (e0 + cc * 4) * 2) = h;
    }
  }
  __syncthreads();

  // ---- transpose x_rm -> ldsB = x^T [128][64] swz ----
  {
    int d = tid & 127, mg = (tid >> 7) * 16;
    #pragma unroll
    for (int mb = 0; mb < 16; mb += 8) {
      us8 v;
      #pragma unroll
      for (int j = 0; j < 8; ++j)
        v[j] = *(const unsigned short*)(ldsC + ((mg + mb + j) << 8) + (d << 1));
      *(us8*)(ldsB + (((d << 7) + ((mg + mb) << 1)) ^ ((d & 7) << 4))) = v;
    }
  }
  __syncthreads();

  // ---- mm1: t = (adj+ep1*I) @ x -> ldsC swz ----
  {
    f32x4 acc[4] = {};
    #pragma unroll
    for (int rt = 0; rt < 4; ++rt) {
      #pragma unroll
      for (int k0 = 0; k0 < 64; k0 += 32) {
        bf16x8 a = frag(ldsAdj, rt * 16 + lr, 64, k0 + lkh * 8);
        bf16x8 b = frag(ldsB, wrow, 64, k0 + lkh * 8);
        acc[rt] = mm(a, b, acc[rt]);
      }
    }
    #pragma unroll
    for (int rt = 0; rt < 4; ++rt) {
      #pragma unroll
      for (int r = 0; r < 4; ++r) {
        int row = rt * 16 + lkh * 4 + r;
        *(unsigned short*)(ldsC + (((row << 8) + (wrow << 1)) ^ ((row & 7) << 4))) = f2b(acc[rt][r]);
      }
    }
  }
  __syncthreads();

  // ---- mm2: u = leaky(t @ W1 + b1) -> ldsB ----
  #pragma unroll
  for (int rt = 0; rt < 4; ++rt) {
    f32x4 acc = {};
    #pragma unroll
    for (int kk = 0; kk < 4; ++kk) {
      bf16x8 a = frag(ldsC, rt * 16 + lr, 128, kk * 32 + lkh * 8);
      acc = mm(a, w1f[kk], acc);
    }
    #pragma unroll
    for (int r = 0; r < 4; ++r) {
      int row = rt * 16 + lkh * 4 + r;
      *(unsigned short*)(ldsB + (((row << 8) + (wrow << 1)) ^ ((row & 7) << 4))) = f2b(lk(acc[r] + bb1));
    }
  }
  __syncthreads();

  // ---- mm3: h = u @ W2 + b2, mask deleted row -> ldsC ----
  #pragma unroll
  for (int rt = 0; rt < 4; ++rt) {
    f32x4 acc = {};
    #pragma unroll
    for (int kk = 0; kk < 4; ++kk) {
      bf16x8 a = frag(ldsB, rt * 16 + lr, 128, kk * 32 + lkh * 8);
      acc = mm(a, w2f[kk], acc);
    }
    #pragma unroll
    for (int r = 0; r < 4; ++r) {
      int row = rt * 16 + lkh * 4 + r;
      float v = acc[r] + bb2;
      if (row == del) v = 0.f;
      *(unsigned short*)(ldsC + (((row << 8) + (wrow << 1)) ^ ((row & 7) << 4))) = f2b(v);
    }
  }
  __syncthreads();

  // ---- global write h + BN per-feature partials ----
  unsigned short* hout = SUB ? h1 + (size_t)bid * 8192 : h2out + (size_t)lb * 8192;
  for (int e = tid * 8; e < 8192; e += 4096) {
    int m = e >> 7, d0 = e & 127;
    us8 v = *(const us8*)(ldsC + (((m << 8) + (d0 << 1)) ^ ((m & 7) << 4)));
    *(us8*)(hout + e) = v;
  }
  {
    int d = tid & 127, q = tid >> 7;
    float sm = 0.f, sq = 0.f;
    for (int m = q * 16; m < q * 16 + 16; ++m) {
      float v = b2f(*(const unsigned short*)(ldsC + (((m << 8) + (d << 1)) ^ ((m & 7) << 4))));
      sm += v; sq += v * v;
    }
    ldsR[tid] = sm; ldsR[512 + tid] = sq;
    __syncthreads();
    if (tid < 128) {
      float* ps = SUB ? p1s + (size_t)bid * 128 : p2s + (size_t)lb * 128;
      float* pq = SUB ? p1q + (size_t)bid * 128 : p2q + (size_t)lb * 128;
      ps[tid] = ldsR[tid] + ldsR[tid + 128] + ldsR[tid + 256] + ldsR[tid + 384];
      pq[tid] = ldsR[512 + tid] + ldsR[640 + tid] + ldsR[768 + tid] + ldsR[896 + tid];
    }
  }
}

// BN stage-1 reduce, coalesced: block b sums rows b*64..+63 of p1s/p1q
__global__ __launch_bounds__(256) void k_bnred(const float* __restrict__ p1s,
    const float* __restrict__ p1q, float* __restrict__ q1s, float* __restrict__ q1q) {
  __shared__ float red[512];
  int b = blockIdx.x, tid = threadIdx.x;
  int d = tid & 127, jh = tid >> 7;
  float s = 0.f, q = 0.f;
  for (int j = b * 64 + jh; j < b * 64 + 64; j += 2) {
    s += p1s[(size_t)j * 128 + d];
    q += p1q[(size_t)j * 128 + d];
  }
  red[tid] = s; red[256 + tid] = q;
  __syncthreads();
  if (tid < 128) {
    q1s[(size_t)b * 128 + d] = red[d] + red[d + 128];
    q1q[(size_t)b * 128 + d] = red[256 + d] + red[384 + d];
  }
}

// Finalize BN into fused scale/shift (deterministic)
__global__ __launch_bounds__(128) void k_bnfin(const float* __restrict__ q1s,
    const float* __restrict__ q1q, const float* __restrict__ p2s,
    const float* __restrict__ p2q, const float* __restrict__ gam1,
    const float* __restrict__ bet1, const float* __restrict__ gam2,
    const float* __restrict__ bet2, float* __restrict__ bnA, float* __restrict__ bnB,
    float* __restrict__ bnsA, float* __restrict__ bnsB) {
  int d = threadIdx.x;
  float s = 0.f, q = 0.f, s2 = 0.f, q2 = 0.f;
  for (int j = 0; j < 64; ++j) {
    s  += q1s[j * 128 + d];  q  += q1q[j * 128 + d];
    s2 += p2s[j * 128 + d];  q2 += p2q[j * 128 + d];
  }
  const float cnt1 = 4096.0f * 63.0f;
  float mean = s / cnt1;
  float var = q / cnt1 - mean * mean;
  float A = gam1[d] * rsqrtf(var + 1e-5f);
  bnA[d] = A; bnB[d] = bet1[d] - mean * A;
  float mean2 = s2 / 4096.0f;
  float var2 = q2 / 4096.0f - mean2 * mean2;
  float A2 = gam2[d] * rsqrtf(var2 + 1e-5f);
  bnsA[d] = A2; bnsB[d] = bet2[d] - mean2 * A2;
}

// final readout MLP per graph, fp32 out
__global__ __launch_bounds__(256) void k_final(const float* __restrict__ ppool,
    const float* __restrict__ W1, const float* __restrict__ b1,
    const float* __restrict__ W2, const float* __restrict__ b2,
    float* __restrict__ out) {
  __shared__ float hg[128];
  __shared__ float z[256];
  int g = blockIdx.x, t = threadIdx.x;
  if (t < 128) {
    float s = 0.f;
    #pragma unroll
    for (int r = 0; r < 16; ++r) s += ppool[(size_t)(g * 16 + r) * 128 + t];
    hg[t] = s * (1.0f / (63.0f * 64.0f));
  }
  __syncthreads();
  float a = b1[t];
  for (int d = 0; d < 128; ++d) a = fmaf(hg[d], W1[d * 256 + t], a);
  z[t] = lk(a);
  __syncthreads();
  if (t < 10) {
    float o = b2[t];
    for (int j = 0; j < 256; ++j) o = fmaf(z[j], W2[j * 10 + t], o);
    out[g * 10 + t] = o;
  }
}

extern "C" void kernel_launch(void* const* d_in, const int* in_sizes, int n_in,
                              void* d_out, int out_size, void* d_ws, size_t ws_size,
                              hipStream_t stream) {
  (void)in_sizes; (void)n_in; (void)out_size; (void)ws_size;
  const float* x    = (const float*)d_in[0];
  const float* adj  = (const float*)d_in[1];
  const float* oadj = (const float*)d_in[2];
  const float* gW1  = (const float*)d_in[3];
  const float* gb1  = (const float*)d_in[4];
  const float* gW2  = (const float*)d_in[5];
  const float* gb2  = (const float*)d_in[6];
  const float* geps = (const float*)d_in[7];
  const float* sW1  = (const float*)d_in[8];
  const float* sb1  = (const float*)d_in[9];
  const float* sW2  = (const float*)d_in[10];
  const float* sb2  = (const float*)d_in[11];
  const float* seps = (const float*)d_in[12];
  const float* bng  = (const float*)d_in[13];
  const float* bnb  = (const float*)d_in[14];
  const float* bnsg = (const float*)d_in[15];
  const float* bnsb = (const float*)d_in[16];
  const float* fW1  = (const float*)d_in[17];
  const float* fb1  = (const float*)d_in[18];
  const float* fW2  = (const float*)d_in[19];
  const float* fb2  = (const float*)d_in[20];
  float* out = (float*)d_out;

  char* w = (char*)d_ws;
  unsigned short* xw   = (unsigned short*)w; w += 67108864;   // x0 bf16 [4096][64][128]
  unsigned short* h1   = (unsigned short*)w; w += 67108864;   // h1 bf16 (in-place per layer)
  unsigned short* h2a  = (unsigned short*)w; w += 1048576;    // h2 ping
  unsigned short* h2b  = (unsigned short*)w; w += 1048576;    // h2 pong
  unsigned short* badj = (unsigned short*)w; w += 2097152;    // adj bits [4096][256]u16
  unsigned short* boadj= (unsigned short*)w; w += 32768;      // oadj bits
  unsigned short* wt   = (unsigned short*)w; w += 524288;     // 16x bf16 [128][128] W^T
  float* pxs  = (float*)w;          w += 8388608;             // xsum partials [256][8192]
  float* p1s  = (float*)w;          w += 2097152;
  float* p1q  = (float*)w;          w += 2097152;
  float* p2s  = (float*)w;          w += 32768;
  float* p2q  = (float*)w;          w += 32768;
  float* q1s  = (float*)w;          w += 32768;
  float* q1q  = (float*)w;          w += 32768;
  float* bnA  = (float*)w;          w += 512;
  float* bnB  = (float*)w;          w += 512;
  float* bnsA = (float*)w;          w += 512;
  float* bnsB = (float*)w;          w += 512;
  float* ppool= (float*)w;          w += 524288;              // pool partials [1024][128]

  unsigned short* h2buf[2] = {h2a, h2b};

  k_prep<<<16, 256, 0, stream>>>(gW1, gW2, sW1, sW2, wt);
  k_pack<<<4096, 256, 0, stream>>>(adj, badj);
  k_pack<<<64, 256, 0, stream>>>(oadj, boadj);
  k_castseg<<<1024, 256, 0, stream>>>(x, xw, pxs);

  for (int i = 0; i < 4; ++i) {
    unsigned short* h2prev = h2buf[(i + 1) & 1];   // layer i-1 output (i>=1)
    unsigned short* h2cur  = h2buf[i & 1];
    if (i > 0)
      k_xpart<0><<<1024, 256, 0, stream>>>(h1, h2prev, bnA, bnB, bnsA, bnsB, pxs, ppool);
    if (i == 0)
      k_gin<1><<<4160, 512, 0, stream>>>(xw, h1, h2prev, h2cur, pxs, badj, boadj,
          wt + 0 * 16384, wt + 1 * 16384, wt + 2 * 16384, wt + 3 * 16384,
          gb1, gb2, sb1, sb2, geps, seps, bnA, bnB, bnsA, bnsB, p1s, p1q, p2s, p2q);
    else
      k_gin<0><<<4160, 512, 0, stream>>>(xw, h1, h2prev, h2cur, pxs, badj, boadj,
          wt + (i * 4 + 0) * 16384, wt + (i * 4 + 1) * 16384,
          wt + (i * 4 + 2) * 16384, wt + (i * 4 + 3) * 16384,
          gb1 + i * 128, gb2 + i * 128, sb1 + i * 128, sb2 + i * 128,
          geps + i, seps + i, bnA, bnB, bnsA, bnsB, p1s, p1q, p2s, p2q);
    k_bnred<<<64, 256, 0, stream>>>(p1s, p1q, q1s, q1q);
    k_bnfin<<<1, 128, 0, stream>>>(q1s, q1q, p2s, p2q, bng + i * 128,
        bnb + i * 128, bnsg + i * 128, bnsb + i * 128, bnA, bnB, bnsA, bnsB);
  }
  k_xpart<1><<<1024, 256, 0, stream>>>(h1, h2buf[1], bnA, bnB, bnsA, bnsB, pxs, ppool);
  k_final<<<64, 256, 0, stream>>>(ppool, fW1, fb1, fW2, fb2, out);
}

// Round 7
// 458.823 us; speedup vs baseline: 2.1817x; 1.1506x over previous
//
#include <hip/hip_runtime.h>
#include <hip/hip_bf16.h>

// DenseDSSnetwork: 4-layer DSS-GIN over 4096 node-deleted subgraphs + graph branch.
// Inputs fp32, OUTPUT fp32 [64,10]. bf16 MFMA (16x16x32), fp32 accumulate.
// Round 7: persistent FEATURE-MAJOR layout hT[d][m] -> no LDS transpose in layers
// 1-3, row-uniform BN consts (scalar loads), BN2 prefused into f32 h2fT (L2-hot),
// BN partials from registers via shfl. k_gin: 4 barriers.

typedef __bf16 bf16x8 __attribute__((ext_vector_type(8)));
typedef float f32x4 __attribute__((ext_vector_type(4)));
typedef unsigned short us8 __attribute__((ext_vector_type(8)));
typedef unsigned short us4 __attribute__((ext_vector_type(4)));

__device__ __forceinline__ unsigned short f2b(float f) {
  unsigned u = __builtin_bit_cast(unsigned, f);
  u += 0x7FFFu + ((u >> 16) & 1u);            // RNE
  return (unsigned short)(u >> 16);
}
__device__ __forceinline__ float b2f(unsigned short h) {
  return __builtin_bit_cast(float, (unsigned)h << 16);
}
__device__ __forceinline__ f32x4 mm(bf16x8 a, bf16x8 b, f32x4 c) {
  return __builtin_amdgcn_mfma_f32_16x16x32_bf16(a, b, c, 0, 0, 0);
}
__device__ __forceinline__ bf16x8 frag(const char* base, int row, int Kelems, int k0) {
  int off = (row * Kelems + k0) * 2;
  off ^= (row & 7) << 4;
  return *(const bf16x8*)(base + off);
}
__device__ __forceinline__ float lk(float v) { return v > 0.f ? v : 0.01f * v; }

// Weight prep: W[k][n] fp32 -> Wt[n][k] bf16, 16 matrices
__global__ __launch_bounds__(256) void k_prep(const float* __restrict__ g1,
    const float* __restrict__ g2, const float* __restrict__ s1,
    const float* __restrict__ s2, unsigned short* __restrict__ wt) {
  int b = blockIdx.x;
  int l = b >> 2, j = b & 3;
  const float* src = (j == 0 ? g1 : j == 1 ? g2 : j == 2 ? s1 : s2) + l * 16384;
  unsigned short* dst = wt + b * 16384;
  for (int e = threadIdx.x; e < 16384; e += 256) {
    int n = e >> 7, k = e & 127;
    dst[e] = f2b(src[k * 128 + n]);
  }
}

// adj fp32 (0/1) -> 1 bit. Per graph: 64 rows x 64 bits = 256 u16.
__global__ __launch_bounds__(256) void k_pack(const float* __restrict__ src,
                                              unsigned short* __restrict__ dst) {
  int sub = blockIdx.x, t = threadIdx.x;
  const float* p = src + (size_t)sub * 4096 + (t >> 2) * 64 + (t & 3) * 16;
  unsigned bits = 0;
  #pragma unroll
  for (int j4 = 0; j4 < 4; ++j4) {
    float4 v = *(const float4*)(p + j4 * 4);
    bits |= (unsigned)(v.x != 0.f) << (j4 * 4);
    bits |= (unsigned)(v.y != 0.f) << (j4 * 4 + 1);
    bits |= (unsigned)(v.z != 0.f) << (j4 * 4 + 2);
    bits |= (unsigned)(v.w != 0.f) << (j4 * 4 + 3);
  }
  dst[(size_t)sub * 256 + t] = (unsigned short)bits;
}

// layer-0: cast x fp32->bf16 AND produce xsum partials (row-major).
__global__ __launch_bounds__(256) void k_castseg(const float* __restrict__ x,
    unsigned short* __restrict__ xw, float* __restrict__ pxs) {
  int b2 = blockIdx.x, bb = b2 >> 2, c = b2 & 3, t = threadIdx.x;
  int e0 = c * 2048 + t * 8;
  float acc[8];
  #pragma unroll
  for (int j = 0; j < 8; ++j) acc[j] = 0.f;
  for (int ss = 0; ss < 16; ++ss) {
    size_t sb = ((size_t)bb * 16 + ss) * 8192 + e0;
    float4 v0 = *(const float4*)(x + sb);
    float4 v1 = *(const float4*)(x + sb + 4);
    acc[0] += v0.x; acc[1] += v0.y; acc[2] += v0.z; acc[3] += v0.w;
    acc[4] += v1.x; acc[5] += v1.y; acc[6] += v1.z; acc[7] += v1.w;
    us8 h;
    h[0] = f2b(v0.x); h[1] = f2b(v0.y); h[2] = f2b(v0.z); h[3] = f2b(v0.w);
    h[4] = f2b(v1.x); h[5] = f2b(v1.y); h[6] = f2b(v1.z); h[7] = f2b(v1.w);
    *(us8*)(xw + sb) = h;
  }
  float* o = pxs + (size_t)bb * 8192 + e0;
  *(float4*)o = make_float4(acc[0], acc[1], acc[2], acc[3]);
  *(float4*)(o + 4) = make_float4(acc[4], acc[5], acc[6], acc[7]);
}

// prefuse BN2 into h2fT (f32, feature-major): h2fT[g][d][m] = A2[d]*h2T + B2[d]
__global__ __launch_bounds__(256) void k_h2fix(const unsigned short* __restrict__ h2T,
    const float* __restrict__ bnsA, const float* __restrict__ bnsB,
    float* __restrict__ h2fT) {
  int idx = blockIdx.x * 256 + threadIdx.x;    // 32768 threads x 16 elems
  int e0 = idx * 16;
  int d = (e0 >> 6) & 127;                     // feature row, uniform per thread
  float A2 = bnsA[d], B2 = bnsB[d];
  us8 v0 = *(const us8*)(h2T + e0);
  us8 v1 = *(const us8*)(h2T + e0 + 8);
  float o[16];
  #pragma unroll
  for (int j = 0; j < 8; ++j) { o[j] = fmaf(b2f(v0[j]), A2, B2); o[8 + j] = fmaf(b2f(v1[j]), A2, B2); }
  #pragma unroll
  for (int c = 0; c < 4; ++c)
    *(float4*)(h2fT + e0 + c * 4) = make_float4(o[c * 4], o[c * 4 + 1], o[c * 4 + 2], o[c * 4 + 3]);
}

// x recompute (feature-major) + segmean partials, or pool partials at LAST.
// block b2: bb=b2>>2 (16 subgraphs), c=b2&3 (feature rows c*32..+32); g=bb>>2.
template<int LAST>
__global__ __launch_bounds__(256) void k_xpart(const unsigned short* __restrict__ h1T,
    const float* __restrict__ h2fT, const float* __restrict__ bnA,
    const float* __restrict__ bnB, float* __restrict__ pxsT,
    float* __restrict__ ppool) {
  int b2 = blockIdx.x, bb = b2 >> 2, c = b2 & 3, g = bb >> 2;
  int t = threadIdx.x;
  int d = c * 32 + (t >> 3), n0 = (t & 7) * 8;
  size_t off = (size_t)d * 64 + n0;
  float A1 = bnA[d], B1 = bnB[d];
  float hb[8];
  *(float4*)hb       = *(const float4*)(h2fT + (size_t)g * 8192 + off);
  *(float4*)(hb + 4) = *(const float4*)(h2fT + (size_t)g * 8192 + off + 4);
  float acc[8];
  #pragma unroll
  for (int j = 0; j < 8; ++j) acc[j] = 0.f;
  for (int ss = 0; ss < 16; ++ss) {
    int s = bb * 16 + ss;
    int del = s & 63;
    us8 a = *(const us8*)(h1T + (size_t)s * 8192 + off);
    #pragma unroll
    for (int j = 0; j < 8; ++j) {
      float hv = ((n0 + j) != del) ? fmaf(b2f(a[j]), A1, B1) : 0.f;
      acc[j] += lk(hv + hb[j]);
    }
  }
  if (!LAST) {
    float* o = pxsT + (size_t)bb * 8192 + off;
    *(float4*)o       = make_float4(acc[0], acc[1], acc[2], acc[3]);
    *(float4*)(o + 4) = make_float4(acc[4], acc[5], acc[6], acc[7]);
  } else {
    float s8 = ((acc[0] + acc[1]) + (acc[2] + acc[3])) + ((acc[4] + acc[5]) + (acc[6] + acc[7]));
    s8 += __shfl_xor(s8, 1, 64);
    s8 += __shfl_xor(s8, 2, 64);
    s8 += __shfl_xor(s8, 4, 64);
    if ((t & 7) == 0) ppool[(size_t)bb * 128 + d] = s8;
  }
}

// Fused GIN, merged grid: blocks 0..4095 subgraph branch, 4096..4159 graph branch.
// FIRST: row-major staging (xw / pxs) + LDS transpose. !FIRST: feature-major
// staging recomputing x^T from h1T (+BN1) and h2fT, straight into ldsB.
// Output: hT[d][m] (feature-major), BN partials from registers.
template<int FIRST>
__global__ __launch_bounds__(512, 4) void k_gin(
    const unsigned short* __restrict__ xw, unsigned short* __restrict__ h1T,
    unsigned short* __restrict__ h2T, const float* __restrict__ h2fT,
    const float* __restrict__ pxs,
    const unsigned short* __restrict__ badj, const unsigned short* __restrict__ boadj,
    const unsigned short* __restrict__ W1g, const unsigned short* __restrict__ W2g,
    const unsigned short* __restrict__ W1s, const unsigned short* __restrict__ W2s,
    const float* __restrict__ b1g, const float* __restrict__ b2g,
    const float* __restrict__ b1s, const float* __restrict__ b2s,
    const float* __restrict__ epg, const float* __restrict__ epss,
    const float* __restrict__ bnA, const float* __restrict__ bnB,
    float* __restrict__ p1s, float* __restrict__ p1q,
    float* __restrict__ p2s, float* __restrict__ p2q) {
  __shared__ __align__(16) char lds[40960];
  char* ldsAdj = lds;              // 8KB : bf16 [64][64] swz (adj + ep1*I)
  char* ldsB   = lds + 8192;       // 16KB: x^T [128][64] swz, then u [64][128] swz
  char* ldsC   = lds + 24576;      // 16KB: FIRST x_rm linear; t [64][128] swz; hT [128][64] swz

  const int tid = threadIdx.x;
  const int bid = blockIdx.x;
  const bool SUB = bid < 4096;
  const int lb = SUB ? bid : bid - 4096;
  const int wv = tid >> 6, ln = tid & 63;
  const int lr = ln & 15, lkh = ln >> 4;
  const int wrow = wv * 16 + lr;
  const float ep1 = 1.0f + (SUB ? epg[0] : epss[0]);
  const int del = SUB ? (bid & 63) : -1;
  const unsigned short* W1t = SUB ? W1g : W1s;
  const unsigned short* W2t = SUB ? W2g : W2s;

  // ---- W fragments into registers ----
  bf16x8 w1f[4], w2f[4];
  #pragma unroll
  for (int kk = 0; kk < 4; ++kk) {
    w1f[kk] = *(const bf16x8*)(W1t + (size_t)wrow * 128 + kk * 32 + lkh * 8);
    w2f[kk] = *(const bf16x8*)(W2t + (size_t)wrow * 128 + kk * 32 + lkh * 8);
  }
  const float bb1 = (SUB ? b1g : b1s)[wrow];
  const float bb2 = (SUB ? b2g : b2s)[wrow];

  // ---- stage adj from bit-pack (+ep1 on diagonal) ----
  {
    const unsigned char* bits =
        (const unsigned char*)(SUB ? badj + (size_t)lb * 256 : boadj + (size_t)lb * 256);
    unsigned char bbt = bits[tid];
    int row = tid >> 3, o = tid & 7;
    unsigned short ep1b = f2b(ep1);
    us8 v;
    #pragma unroll
    for (int j = 0; j < 8; ++j) v[j] = ((bbt >> j) & 1) ? (unsigned short)0x3F80 : (unsigned short)0;
    int j0 = row - o * 8;
    if (j0 >= 0 && j0 < 8) v[j0] = ep1b;
    int e = tid * 8;
    *(us8*)(ldsAdj + ((e << 1) ^ ((row & 7) << 4))) = v;
  }
  // ---- stage x ----
  if (FIRST) {
    if (SUB) {
      const unsigned short* xg = xw + (size_t)bid * 8192;
      for (int e = tid * 8; e < 8192; e += 4096)
        *(us8*)(ldsC + e * 2) = *(const us8*)(xg + e);
    } else {
      const float* p = pxs + (size_t)lb * 4 * 8192;
      int e0 = tid * 16;
      #pragma unroll
      for (int cc = 0; cc < 4; ++cc) {
        float4 s = {0.f, 0.f, 0.f, 0.f};
        #pragma unroll
        for (int qt = 0; qt < 4; ++qt) {
          float4 v = *(const float4*)(p + qt * 8192 + e0 + cc * 4);
          s.x += v.x; s.y += v.y; s.z += v.z; s.w += v.w;
        }
        us4 h; h.x = f2b(s.x * 0.015625f); h.y = f2b(s.y * 0.015625f);
        h.z = f2b(s.z * 0.015625f); h.w = f2b(s.w * 0.015625f);
        *(us4*)(ldsC + (e0 + cc * 4) * 2) = h;
      }
    }
    __syncthreads();
    // transpose x_rm -> ldsB = x^T [128][64] swz
    int d = tid & 127, mg = (tid >> 7) * 16;
    #pragma unroll
    for (int mb = 0; mb < 16; mb += 8) {
      us8 v;
      #pragma unroll
      for (int j = 0; j < 8; ++j)
        v[j] = *(const unsigned short*)(ldsC + ((mg + mb + j) << 8) + (d << 1));
      *(us8*)(ldsB + (((d << 7) + ((mg + mb) << 1)) ^ ((d & 7) << 4))) = v;
    }
  } else {
    int d = tid >> 2, n0 = (tid & 3) * 16;    // feature row, 16 nodes
    if (SUB) {
      const unsigned short* h1g = h1T + (size_t)bid * 8192 + d * 64 + n0;
      const float* h2g = h2fT + (size_t)(bid >> 6) * 8192 + d * 64 + n0;
      float A1 = bnA[d], B1 = bnB[d];
      #pragma unroll
      for (int cc = 0; cc < 2; ++cc) {
        us8 a = *(const us8*)(h1g + cc * 8);
        float hb[8];
        *(float4*)hb       = *(const float4*)(h2g + cc * 8);
        *(float4*)(hb + 4) = *(const float4*)(h2g + cc * 8 + 4);
        us8 o;
        #pragma unroll
        for (int j = 0; j < 8; ++j) {
          int m = n0 + cc * 8 + j;
          float hv = (m != del) ? fmaf(b2f(a[j]), A1, B1) : 0.f;
          o[j] = f2b(lk(hv + hb[j]));
        }
        *(us8*)(ldsB + (((d * 64 + n0 + cc * 8) * 2) ^ ((d & 7) << 4))) = o;
      }
    } else {
      const float* p = pxs + (size_t)lb * 4 * 8192 + d * 64 + n0;  // pxsT
      #pragma unroll
      for (int cc = 0; cc < 4; ++cc) {
        float4 s = {0.f, 0.f, 0.f, 0.f};
        #pragma unroll
        for (int qt = 0; qt < 4; ++qt) {
          float4 v = *(const float4*)(p + qt * 8192 + cc * 4);
          s.x += v.x; s.y += v.y; s.z += v.z; s.w += v.w;
        }
        us4 h; h.x = f2b(s.x * 0.015625f); h.y = f2b(s.y * 0.015625f);
        h.z = f2b(s.z * 0.015625f); h.w = f2b(s.w * 0.015625f);
        *(us4*)(ldsB + (((d * 64 + n0 + cc * 4) * 2) ^ ((d & 7) << 4))) = h;
      }
    }
  }
  __syncthreads();

  // ---- mm1: t = (adj+ep1*I) @ x -> ldsC [64][128] swz ----
  {
    f32x4 acc[4] = {};
    #pragma unroll
    for (int rt = 0; rt < 4; ++rt) {
      #pragma unroll
      for (int k0 = 0; k0 < 64; k0 += 32) {
        bf16x8 a = frag(ldsAdj, rt * 16 + lr, 64, k0 + lkh * 8);
        bf16x8 b = frag(ldsB, wrow, 64, k0 + lkh * 8);
        acc[rt] = mm(a, b, acc[rt]);
      }
    }
    #pragma unroll
    for (int rt = 0; rt < 4; ++rt) {
      #pragma unroll
      for (int r = 0; r < 4; ++r) {
        int row = rt * 16 + lkh * 4 + r;
        *(unsigned short*)(ldsC + (((row << 8) + (wrow << 1)) ^ ((row & 7) << 4))) = f2b(acc[rt][r]);
      }
    }
  }
  __syncthreads();

  // ---- mm2: u = leaky(t @ W1 + b1) -> ldsB [64][128] swz ----
  #pragma unroll
  for (int rt = 0; rt < 4; ++rt) {
    f32x4 acc = {};
    #pragma unroll
    for (int kk = 0; kk < 4; ++kk) {
      bf16x8 a = frag(ldsC, rt * 16 + lr, 128, kk * 32 + lkh * 8);
      acc = mm(a, w1f[kk], acc);
    }
    #pragma unroll
    for (int r = 0; r < 4; ++r) {
      int row = rt * 16 + lkh * 4 + r;
      *(unsigned short*)(ldsB + (((row << 8) + (wrow << 1)) ^ ((row & 7) << 4))) = f2b(lk(acc[r] + bb1));
    }
  }
  __syncthreads();

  // ---- mm3: h = u @ W2 + b2, mask; write hT [128][64] swz + reg BN partials ----
  {
    float sm = 0.f, sq = 0.f;
    #pragma unroll
    for (int rt = 0; rt < 4; ++rt) {
      f32x4 acc = {};
      #pragma unroll
      for (int kk = 0; kk < 4; ++kk) {
        bf16x8 a = frag(ldsB, rt * 16 + lr, 128, kk * 32 + lkh * 8);
        acc = mm(a, w2f[kk], acc);
      }
      us4 h4;
      #pragma unroll
      for (int r = 0; r < 4; ++r) {
        int m = rt * 16 + lkh * 4 + r;
        float v = acc[r] + bb2;
        if (m == del) v = 0.f;
        sm += v; sq += v * v;
        h4[r] = f2b(v);
      }
      *(us4*)(ldsC + (((wrow * 64 + rt * 16 + lkh * 4) * 2) ^ ((wrow & 7) << 4))) = h4;
    }
    sm += __shfl_xor(sm, 16, 64); sm += __shfl_xor(sm, 32, 64);
    sq += __shfl_xor(sq, 16, 64); sq += __shfl_xor(sq, 32, 64);
    if (ln < 16) {
      float* ps = SUB ? p1s + (size_t)bid * 128 : p2s + (size_t)lb * 128;
      float* pq = SUB ? p1q + (size_t)bid * 128 : p2q + (size_t)lb * 128;
      ps[wrow] = sm;
      pq[wrow] = sq;
    }
  }
  __syncthreads();

  // ---- global write hT (linear) ----
  unsigned short* hout = SUB ? h1T + (size_t)bid * 8192 : h2T + (size_t)lb * 8192;
  {
    int e0 = tid * 16;
    int d = e0 >> 6;
    *(us8*)(hout + e0)     = *(const us8*)(ldsC + (((e0)     * 2) ^ ((d & 7) << 4)));
    *(us8*)(hout + e0 + 8) = *(const us8*)(ldsC + (((e0 + 8) * 2) ^ ((d & 7) << 4)));
  }
}

// BN stage-1 reduce, coalesced
__global__ __launch_bounds__(256) void k_bnred(const float* __restrict__ p1s,
    const float* __restrict__ p1q, float* __restrict__ q1s, float* __restrict__ q1q) {
  __shared__ float red[512];
  int b = blockIdx.x, tid = threadIdx.x;
  int d = tid & 127, jh = tid >> 7;
  float s = 0.f, q = 0.f;
  for (int j = b * 64 + jh; j < b * 64 + 64; j += 2) {
    s += p1s[(size_t)j * 128 + d];
    q += p1q[(size_t)j * 128 + d];
  }
  red[tid] = s; red[256 + tid] = q;
  __syncthreads();
  if (tid < 128) {
    q1s[(size_t)b * 128 + d] = red[d] + red[d + 128];
    q1q[(size_t)b * 128 + d] = red[256 + d] + red[384 + d];
  }
}

// Finalize BN into fused scale/shift
__global__ __launch_bounds__(128) void k_bnfin(const float* __restrict__ q1s,
    const float* __restrict__ q1q, const float* __restrict__ p2s,
    const float* __restrict__ p2q, const float* __restrict__ gam1,
    const float* __restrict__ bet1, const float* __restrict__ gam2,
    const float* __restrict__ bet2, float* __restrict__ bnA, float* __restrict__ bnB,
    float* __restrict__ bnsA, float* __restrict__ bnsB) {
  int d = threadIdx.x;
  float s = 0.f, q = 0.f, s2 = 0.f, q2 = 0.f;
  for (int j = 0; j < 64; ++j) {
    s  += q1s[j * 128 + d];  q  += q1q[j * 128 + d];
    s2 += p2s[j * 128 + d];  q2 += p2q[j * 128 + d];
  }
  const float cnt1 = 4096.0f * 63.0f;
  float mean = s / cnt1;
  float var = q / cnt1 - mean * mean;
  float A = gam1[d] * rsqrtf(var + 1e-5f);
  bnA[d] = A; bnB[d] = bet1[d] - mean * A;
  float mean2 = s2 / 4096.0f;
  float var2 = q2 / 4096.0f - mean2 * mean2;
  float A2 = gam2[d] * rsqrtf(var2 + 1e-5f);
  bnsA[d] = A2; bnsB[d] = bet2[d] - mean2 * A2;
}

// final readout MLP per graph, fp32 out
__global__ __launch_bounds__(256) void k_final(const float* __restrict__ ppool,
    const float* __restrict__ W1, const float* __restrict__ b1,
    const float* __restrict__ W2, const float* __restrict__ b2,
    float* __restrict__ out) {
  __shared__ float hg[128];
  __shared__ float z[256];
  int g = blockIdx.x, t = threadIdx.x;
  if (t < 128) {
    float s = ppool[(size_t)(g * 4 + 0) * 128 + t] + ppool[(size_t)(g * 4 + 1) * 128 + t]
            + ppool[(size_t)(g * 4 + 2) * 128 + t] + ppool[(size_t)(g * 4 + 3) * 128 + t];
    hg[t] = s * (1.0f / (63.0f * 64.0f));
  }
  __syncthreads();
  float a = b1[t];
  for (int d = 0; d < 128; ++d) a = fmaf(hg[d], W1[d * 256 + t], a);
  z[t] = lk(a);
  __syncthreads();
  if (t < 10) {
    float o = b2[t];
    for (int j = 0; j < 256; ++j) o = fmaf(z[j], W2[j * 10 + t], o);
    out[g * 10 + t] = o;
  }
}

extern "C" void kernel_launch(void* const* d_in, const int* in_sizes, int n_in,
                              void* d_out, int out_size, void* d_ws, size_t ws_size,
                              hipStream_t stream) {
  (void)in_sizes; (void)n_in; (void)out_size; (void)ws_size;
  const float* x    = (const float*)d_in[0];
  const float* adj  = (const float*)d_in[1];
  const float* oadj = (const float*)d_in[2];
  const float* gW1  = (const float*)d_in[3];
  const float* gb1  = (const float*)d_in[4];
  const float* gW2  = (const float*)d_in[5];
  const float* gb2  = (const float*)d_in[6];
  const float* geps = (const float*)d_in[7];
  const float* sW1  = (const float*)d_in[8];
  const float* sb1  = (const float*)d_in[9];
  const float* sW2  = (const float*)d_in[10];
  const float* sb2  = (const float*)d_in[11];
  const float* seps = (const float*)d_in[12];
  const float* bng  = (const float*)d_in[13];
  const float* bnb  = (const float*)d_in[14];
  const float* bnsg = (const float*)d_in[15];
  const float* bnsb = (const float*)d_in[16];
  const float* fW1  = (const float*)d_in[17];
  const float* fb1  = (const float*)d_in[18];
  const float* fW2  = (const float*)d_in[19];
  const float* fb2  = (const float*)d_in[20];
  float* out = (float*)d_out;

  char* w = (char*)d_ws;
  unsigned short* xw   = (unsigned short*)w; w += 67108864;   // x0 bf16 row-major
  unsigned short* h1T  = (unsigned short*)w; w += 67108864;   // h1 bf16 feature-major
  unsigned short* h2T  = (unsigned short*)w; w += 1048576;    // h2 bf16 feature-major
  unsigned short* badj = (unsigned short*)w; w += 2097152;    // adj bits
  unsigned short* boadj= (unsigned short*)w; w += 32768;      // oadj bits
  unsigned short* wt   = (unsigned short*)w; w += 524288;     // 16x W^T bf16
  float* h2fT = (float*)w;          w += 2097152;             // BN2(h2) f32 feat-major
  float* pxs  = (float*)w;          w += 8388608;             // xsum partials [256][8192]
  float* p1s  = (float*)w;          w += 2097152;
  float* p1q  = (float*)w;          w += 2097152;
  float* p2s  = (float*)w;          w += 32768;
  float* p2q  = (float*)w;          w += 32768;
  float* q1s  = (float*)w;          w += 32768;
  float* q1q  = (float*)w;          w += 32768;
  float* bnA  = (float*)w;          w += 512;
  float* bnB  = (float*)w;          w += 512;
  float* bnsA = (float*)w;          w += 512;
  float* bnsB = (float*)w;          w += 512;
  float* ppool= (float*)w;          w += 131072;              // [256][128]

  k_prep<<<16, 256, 0, stream>>>(gW1, gW2, sW1, sW2, wt);
  k_pack<<<4096, 256, 0, stream>>>(adj, badj);
  k_pack<<<64, 256, 0, stream>>>(oadj, boadj);
  k_castseg<<<1024, 256, 0, stream>>>(x, xw, pxs);

  for (int i = 0; i < 4; ++i) {
    if (i > 0)
      k_xpart<0><<<1024, 256, 0, stream>>>(h1T, h2fT, bnA, bnB, pxs, ppool);
    if (i == 0)
      k_gin<1><<<4160, 512, 0, stream>>>(xw, h1T, h2T, h2fT, pxs, badj, boadj,
          wt + 0 * 16384, wt + 1 * 16384, wt + 2 * 16384, wt + 3 * 16384,
          gb1, gb2, sb1, sb2, geps, seps, bnA, bnB, p1s, p1q, p2s, p2q);
    else
      k_gin<0><<<4160, 512, 0, stream>>>(xw, h1T, h2T, h2fT, pxs, badj, boadj,
          wt + (i * 4 + 0) * 16384, wt + (i * 4 + 1) * 16384,
          wt + (i * 4 + 2) * 16384, wt + (i * 4 + 3) * 16384,
          gb1 + i * 128, gb2 + i * 128, sb1 + i * 128, sb2 + i * 128,
          geps + i, seps + i, bnA, bnB, p1s, p1q, p2s, p2q);
    k_bnred<<<64, 256, 0, stream>>>(p1s, p1q, q1s, q1q);
    k_bnfin<<<1, 128, 0, stream>>>(q1s, q1q, p2s, p2q, bng + i * 128,
        bnb + i * 128, bnsg + i * 128, bnsb + i * 128, bnA, bnB, bnsA, bnsB);
    k_h2fix<<<128, 256, 0, stream>>>(h2T, bnsA, bnsB, h2fT);
  }
  k_xpart<1><<<1024, 256, 0, stream>>>(h1T, h2fT, bnA, bnB, pxs, ppool);
  k_final<<<64, 256, 0, stream>>>(ppool, fW1, fb1, fW2, fb2, out);
}

// Round 8
// 422.407 us; speedup vs baseline: 2.3697x; 1.0862x over previous
//
#include <hip/hip_runtime.h>
#include <hip/hip_bf16.h>

// DenseDSSnetwork: 4-layer DSS-GIN over 4096 node-deleted subgraphs + graph branch.
// Inputs fp32, OUTPUT fp32 [64,10]. bf16 MFMA (16x16x32), fp32 accumulate.
// Round 8: v_cvt_pk_bf16_f32 for all hot f32->bf16 (1 inst / 2 vals, RNE);
// h2fix/h2fT removed (row-uniform BN2 consts read as scalars); h2 ping-pong back.

typedef __bf16 bf16x8 __attribute__((ext_vector_type(8)));
typedef float f32x4 __attribute__((ext_vector_type(4)));
typedef unsigned short us8 __attribute__((ext_vector_type(8)));
typedef unsigned short us4 __attribute__((ext_vector_type(4)));
typedef unsigned u32x4 __attribute__((ext_vector_type(4)));
typedef unsigned u32x2 __attribute__((ext_vector_type(2)));

__device__ __forceinline__ unsigned short f2b(float f) {
  unsigned u = __builtin_bit_cast(unsigned, f);
  u += 0x7FFFu + ((u >> 16) & 1u);            // RNE (cold paths)
  return (unsigned short)(u >> 16);
}
// HW packed convert: lo -> bits[15:0], hi -> bits[31:16], RNE
__device__ __forceinline__ unsigned cvtpk(float lo, float hi) {
  unsigned r;
  asm("v_cvt_pk_bf16_f32 %0, %1, %2" : "=v"(r) : "v"(lo), "v"(hi));
  return r;
}
__device__ __forceinline__ float b2f(unsigned short h) {
  return __builtin_bit_cast(float, (unsigned)h << 16);
}
__device__ __forceinline__ f32x4 mm(bf16x8 a, bf16x8 b, f32x4 c) {
  return __builtin_amdgcn_mfma_f32_16x16x32_bf16(a, b, c, 0, 0, 0);
}
__device__ __forceinline__ bf16x8 frag(const char* base, int row, int Kelems, int k0) {
  int off = (row * Kelems + k0) * 2;
  off ^= (row & 7) << 4;
  return *(const bf16x8*)(base + off);
}
__device__ __forceinline__ float lk(float v) { return fmaxf(v, 0.01f * v); }

// Weight prep: W[k][n] fp32 -> Wt[n][k] bf16, 16 matrices
__global__ __launch_bounds__(256) void k_prep(const float* __restrict__ g1,
    const float* __restrict__ g2, const float* __restrict__ s1,
    const float* __restrict__ s2, unsigned short* __restrict__ wt) {
  int b = blockIdx.x;
  int l = b >> 2, j = b & 3;
  const float* src = (j == 0 ? g1 : j == 1 ? g2 : j == 2 ? s1 : s2) + l * 16384;
  unsigned short* dst = wt + b * 16384;
  for (int e = threadIdx.x; e < 16384; e += 256) {
    int n = e >> 7, k = e & 127;
    dst[e] = f2b(src[k * 128 + n]);
  }
}

// adj fp32 (0/1) -> 1 bit. Per graph: 64 rows x 64 bits = 256 u16.
__global__ __launch_bounds__(256) void k_pack(const float* __restrict__ src,
                                              unsigned short* __restrict__ dst) {
  int sub = blockIdx.x, t = threadIdx.x;
  const float* p = src + (size_t)sub * 4096 + (t >> 2) * 64 + (t & 3) * 16;
  unsigned bits = 0;
  #pragma unroll
  for (int j4 = 0; j4 < 4; ++j4) {
    float4 v = *(const float4*)(p + j4 * 4);
    bits |= (unsigned)(v.x != 0.f) << (j4 * 4);
    bits |= (unsigned)(v.y != 0.f) << (j4 * 4 + 1);
    bits |= (unsigned)(v.z != 0.f) << (j4 * 4 + 2);
    bits |= (unsigned)(v.w != 0.f) << (j4 * 4 + 3);
  }
  dst[(size_t)sub * 256 + t] = (unsigned short)bits;
}

// layer-0: cast x fp32->bf16 AND produce xsum partials (row-major).
__global__ __launch_bounds__(256) void k_castseg(const float* __restrict__ x,
    unsigned short* __restrict__ xw, float* __restrict__ pxs) {
  int b2 = blockIdx.x, bb = b2 >> 2, c = b2 & 3, t = threadIdx.x;
  int e0 = c * 2048 + t * 8;
  float acc[8];
  #pragma unroll
  for (int j = 0; j < 8; ++j) acc[j] = 0.f;
  for (int ss = 0; ss < 16; ++ss) {
    size_t sb = ((size_t)bb * 16 + ss) * 8192 + e0;
    float4 v0 = *(const float4*)(x + sb);
    float4 v1 = *(const float4*)(x + sb + 4);
    acc[0] += v0.x; acc[1] += v0.y; acc[2] += v0.z; acc[3] += v0.w;
    acc[4] += v1.x; acc[5] += v1.y; acc[6] += v1.z; acc[7] += v1.w;
    u32x4 pk;
    pk.x = cvtpk(v0.x, v0.y); pk.y = cvtpk(v0.z, v0.w);
    pk.z = cvtpk(v1.x, v1.y); pk.w = cvtpk(v1.z, v1.w);
    *(us8*)(xw + sb) = __builtin_bit_cast(us8, pk);
  }
  float* o = pxs + (size_t)bb * 8192 + e0;
  *(float4*)o = make_float4(acc[0], acc[1], acc[2], acc[3]);
  *(float4*)(o + 4) = make_float4(acc[4], acc[5], acc[6], acc[7]);
}

// x recompute (feature-major) + segmean partials, or pool partials at LAST.
// block b2: bb=b2>>2 (16 subgraphs), c=b2&3 (feature rows c*32..+32); g=bb>>2.
template<int LAST>
__global__ __launch_bounds__(256) void k_xpart(const unsigned short* __restrict__ h1T,
    const unsigned short* __restrict__ h2T, const float* __restrict__ bnA,
    const float* __restrict__ bnB, const float* __restrict__ bnsA,
    const float* __restrict__ bnsB, float* __restrict__ pxsT,
    float* __restrict__ ppool) {
  int b2 = blockIdx.x, bb = b2 >> 2, c = b2 & 3, g = bb >> 2;
  int t = threadIdx.x;
  int d = c * 32 + (t >> 3), n0 = (t & 7) * 8;
  size_t off = (size_t)d * 64 + n0;
  float A1 = bnA[d], B1 = bnB[d];
  float A2 = bnsA[d], B2 = bnsB[d];
  float hb[8];
  {
    us8 v = *(const us8*)(h2T + (size_t)g * 8192 + off);
    #pragma unroll
    for (int j = 0; j < 8; ++j) hb[j] = fmaf(b2f(v[j]), A2, B2);
  }
  float acc[8];
  #pragma unroll
  for (int j = 0; j < 8; ++j) acc[j] = 0.f;
  for (int ss = 0; ss < 16; ++ss) {
    int s = bb * 16 + ss;
    int del = s & 63;
    us8 a = *(const us8*)(h1T + (size_t)s * 8192 + off);
    #pragma unroll
    for (int j = 0; j < 8; ++j) {
      float hv = ((n0 + j) != del) ? fmaf(b2f(a[j]), A1, B1) : 0.f;
      acc[j] += lk(hv + hb[j]);
    }
  }
  if (!LAST) {
    float* o = pxsT + (size_t)bb * 8192 + off;
    *(float4*)o       = make_float4(acc[0], acc[1], acc[2], acc[3]);
    *(float4*)(o + 4) = make_float4(acc[4], acc[5], acc[6], acc[7]);
  } else {
    float s8 = ((acc[0] + acc[1]) + (acc[2] + acc[3])) + ((acc[4] + acc[5]) + (acc[6] + acc[7]));
    s8 += __shfl_xor(s8, 1, 64);
    s8 += __shfl_xor(s8, 2, 64);
    s8 += __shfl_xor(s8, 4, 64);
    if ((t & 7) == 0) ppool[(size_t)bb * 128 + d] = s8;
  }
}

// Fused GIN, merged grid: blocks 0..4095 subgraph branch, 4096..4159 graph branch.
// FIRST: row-major staging (xw / pxs row-major) + LDS transpose. !FIRST:
// feature-major staging recomputing x^T from h1T (+BN1) and h2prev (+BN2 scalar).
// Output: hT[d][m] (feature-major), BN partials from registers.
template<int FIRST>
__global__ __launch_bounds__(512, 4) void k_gin(
    const unsigned short* __restrict__ xw, unsigned short* __restrict__ h1T,
    const unsigned short* __restrict__ h2prev, unsigned short* __restrict__ h2out,
    const float* __restrict__ pxs,
    const unsigned short* __restrict__ badj, const unsigned short* __restrict__ boadj,
    const unsigned short* __restrict__ W1g, const unsigned short* __restrict__ W2g,
    const unsigned short* __restrict__ W1s, const unsigned short* __restrict__ W2s,
    const float* __restrict__ b1g, const float* __restrict__ b2g,
    const float* __restrict__ b1s, const float* __restrict__ b2s,
    const float* __restrict__ epg, const float* __restrict__ epss,
    const float* __restrict__ bnA, const float* __restrict__ bnB,
    const float* __restrict__ bnsA, const float* __restrict__ bnsB,
    float* __restrict__ p1s, float* __restrict__ p1q,
    float* __restrict__ p2s, float* __restrict__ p2q) {
  __shared__ __align__(16) char lds[40960];
  char* ldsAdj = lds;              // 8KB : bf16 [64][64] swz (adj + ep1*I)
  char* ldsB   = lds + 8192;       // 16KB: x^T [128][64] swz, then u [64][128] swz
  char* ldsC   = lds + 24576;      // 16KB: FIRST x_rm linear; t [64][128] swz; hT [128][64] swz

  const int tid = threadIdx.x;
  const int bid = blockIdx.x;
  const bool SUB = bid < 4096;
  const int lb = SUB ? bid : bid - 4096;
  const int wv = tid >> 6, ln = tid & 63;
  const int lr = ln & 15, lkh = ln >> 4;
  const int wrow = wv * 16 + lr;
  const float ep1 = 1.0f + (SUB ? epg[0] : epss[0]);
  const int del = SUB ? (bid & 63) : -1;
  const unsigned short* W1t = SUB ? W1g : W1s;
  const unsigned short* W2t = SUB ? W2g : W2s;

  // ---- W fragments into registers ----
  bf16x8 w1f[4], w2f[4];
  #pragma unroll
  for (int kk = 0; kk < 4; ++kk) {
    w1f[kk] = *(const bf16x8*)(W1t + (size_t)wrow * 128 + kk * 32 + lkh * 8);
    w2f[kk] = *(const bf16x8*)(W2t + (size_t)wrow * 128 + kk * 32 + lkh * 8);
  }
  const float bb1 = (SUB ? b1g : b1s)[wrow];
  const float bb2 = (SUB ? b2g : b2s)[wrow];

  // ---- stage adj from bit-pack (+ep1 on diagonal) ----
  {
    const unsigned char* bits =
        (const unsigned char*)(SUB ? badj + (size_t)lb * 256 : boadj + (size_t)lb * 256);
    unsigned char bbt = bits[tid];
    int row = tid >> 3, o = tid & 7;
    unsigned short ep1b = f2b(ep1);
    us8 v;
    #pragma unroll
    for (int j = 0; j < 8; ++j) v[j] = ((bbt >> j) & 1) ? (unsigned short)0x3F80 : (unsigned short)0;
    int j0 = row - o * 8;
    if (j0 >= 0 && j0 < 8) v[j0] = ep1b;
    int e = tid * 8;
    *(us8*)(ldsAdj + ((e << 1) ^ ((row & 7) << 4))) = v;
  }
  // ---- stage x ----
  if (FIRST) {
    if (SUB) {
      const unsigned short* xg = xw + (size_t)bid * 8192;
      for (int e = tid * 8; e < 8192; e += 4096)
        *(us8*)(ldsC + e * 2) = *(const us8*)(xg + e);
    } else {
      const float* p = pxs + (size_t)lb * 4 * 8192;
      int e0 = tid * 16;
      #pragma unroll
      for (int cc = 0; cc < 4; ++cc) {
        float4 s = {0.f, 0.f, 0.f, 0.f};
        #pragma unroll
        for (int qt = 0; qt < 4; ++qt) {
          float4 v = *(const float4*)(p + qt * 8192 + e0 + cc * 4);
          s.x += v.x; s.y += v.y; s.z += v.z; s.w += v.w;
        }
        u32x2 pk;
        pk.x = cvtpk(s.x * 0.015625f, s.y * 0.015625f);
        pk.y = cvtpk(s.z * 0.015625f, s.w * 0.015625f);
        *(us4*)(ldsC + (e0 + cc * 4) * 2) = __builtin_bit_cast(us4, pk);
      }
    }
    __syncthreads();
    // transpose x_rm -> ldsB = x^T [128][64] swz
    int d = tid & 127, mg = (tid >> 7) * 16;
    #pragma unroll
    for (int mb = 0; mb < 16; mb += 8) {
      us8 v;
      #pragma unroll
      for (int j = 0; j < 8; ++j)
        v[j] = *(const unsigned short*)(ldsC + ((mg + mb + j) << 8) + (d << 1));
      *(us8*)(ldsB + (((d << 7) + ((mg + mb) << 1)) ^ ((d & 7) << 4))) = v;
    }
  } else {
    int d = tid >> 2, n0 = (tid & 3) * 16;    // feature row, 16 nodes
    if (SUB) {
      const unsigned short* h1g = h1T + (size_t)bid * 8192 + d * 64 + n0;
      const unsigned short* h2g = h2prev + (size_t)(bid >> 6) * 8192 + d * 64 + n0;
      float A1 = bnA[d], B1 = bnB[d];
      float A2 = bnsA[d], B2 = bnsB[d];
      #pragma unroll
      for (int cc = 0; cc < 2; ++cc) {
        us8 a = *(const us8*)(h1g + cc * 8);
        us8 b = *(const us8*)(h2g + cc * 8);
        float xv[8];
        #pragma unroll
        for (int j = 0; j < 8; ++j) {
          int m = n0 + cc * 8 + j;
          float hv = (m != del) ? fmaf(b2f(a[j]), A1, B1) : 0.f;
          xv[j] = lk(hv + fmaf(b2f(b[j]), A2, B2));
        }
        u32x4 pk;
        pk.x = cvtpk(xv[0], xv[1]); pk.y = cvtpk(xv[2], xv[3]);
        pk.z = cvtpk(xv[4], xv[5]); pk.w = cvtpk(xv[6], xv[7]);
        *(us8*)(ldsB + (((d * 64 + n0 + cc * 8) * 2) ^ ((d & 7) << 4))) = __builtin_bit_cast(us8, pk);
      }
    } else {
      const float* p = pxs + (size_t)lb * 4 * 8192 + d * 64 + n0;  // pxsT
      #pragma unroll
      for (int cc = 0; cc < 4; ++cc) {
        float4 s = {0.f, 0.f, 0.f, 0.f};
        #pragma unroll
        for (int qt = 0; qt < 4; ++qt) {
          float4 v = *(const float4*)(p + qt * 8192 + cc * 4);
          s.x += v.x; s.y += v.y; s.z += v.z; s.w += v.w;
        }
        u32x2 pk;
        pk.x = cvtpk(s.x * 0.015625f, s.y * 0.015625f);
        pk.y = cvtpk(s.z * 0.015625f, s.w * 0.015625f);
        *(us4*)(ldsB + (((d * 64 + n0 + cc * 4) * 2) ^ ((d & 7) << 4))) = __builtin_bit_cast(us4, pk);
      }
    }
  }
  __syncthreads();

  // ---- mm1: t = (adj+ep1*I) @ x -> ldsC [64][128] swz ----
  {
    f32x4 acc[4] = {};
    #pragma unroll
    for (int rt = 0; rt < 4; ++rt) {
      #pragma unroll
      for (int k0 = 0; k0 < 64; k0 += 32) {
        bf16x8 a = frag(ldsAdj, rt * 16 + lr, 64, k0 + lkh * 8);
        bf16x8 b = frag(ldsB, wrow, 64, k0 + lkh * 8);
        acc[rt] = mm(a, b, acc[rt]);
      }
    }
    #pragma unroll
    for (int rt = 0; rt < 4; ++rt) {
      unsigned p01 = cvtpk(acc[rt][0], acc[rt][1]);
      unsigned p23 = cvtpk(acc[rt][2], acc[rt][3]);
      int r0 = rt * 16 + lkh * 4;
      *(unsigned short*)(ldsC + ((((r0 + 0) << 8) + (wrow << 1)) ^ (((r0 + 0) & 7) << 4))) = (unsigned short)p01;
      *(unsigned short*)(ldsC + ((((r0 + 1) << 8) + (wrow << 1)) ^ (((r0 + 1) & 7) << 4))) = (unsigned short)(p01 >> 16);
      *(unsigned short*)(ldsC + ((((r0 + 2) << 8) + (wrow << 1)) ^ (((r0 + 2) & 7) << 4))) = (unsigned short)p23;
      *(unsigned short*)(ldsC + ((((r0 + 3) << 8) + (wrow << 1)) ^ (((r0 + 3) & 7) << 4))) = (unsigned short)(p23 >> 16);
    }
  }
  __syncthreads();

  // ---- mm2: u = leaky(t @ W1 + b1) -> ldsB [64][128] swz ----
  #pragma unroll
  for (int rt = 0; rt < 4; ++rt) {
    f32x4 acc = {};
    #pragma unroll
    for (int kk = 0; kk < 4; ++kk) {
      bf16x8 a = frag(ldsC, rt * 16 + lr, 128, kk * 32 + lkh * 8);
      acc = mm(a, w1f[kk], acc);
    }
    float u0 = lk(acc[0] + bb1), u1 = lk(acc[1] + bb1);
    float u2 = lk(acc[2] + bb1), u3 = lk(acc[3] + bb1);
    unsigned p01 = cvtpk(u0, u1);
    unsigned p23 = cvtpk(u2, u3);
    int r0 = rt * 16 + lkh * 4;
    *(unsigned short*)(ldsB + ((((r0 + 0) << 8) + (wrow << 1)) ^ (((r0 + 0) & 7) << 4))) = (unsigned short)p01;
    *(unsigned short*)(ldsB + ((((r0 + 1) << 8) + (wrow << 1)) ^ (((r0 + 1) & 7) << 4))) = (unsigned short)(p01 >> 16);
    *(unsigned short*)(ldsB + ((((r0 + 2) << 8) + (wrow << 1)) ^ (((r0 + 2) & 7) << 4))) = (unsigned short)p23;
    *(unsigned short*)(ldsB + ((((r0 + 3) << 8) + (wrow << 1)) ^ (((r0 + 3) & 7) << 4))) = (unsigned short)(p23 >> 16);
  }
  __syncthreads();

  // ---- mm3: h = u @ W2 + b2, mask; write hT [128][64] swz + reg BN partials ----
  {
    float sm = 0.f, sq = 0.f;
    #pragma unroll
    for (int rt = 0; rt < 4; ++rt) {
      f32x4 acc = {};
      #pragma unroll
      for (int kk = 0; kk < 4; ++kk) {
        bf16x8 a = frag(ldsB, rt * 16 + lr, 128, kk * 32 + lkh * 8);
        acc = mm(a, w2f[kk], acc);
      }
      float v0 = acc[0] + bb2, v1 = acc[1] + bb2, v2 = acc[2] + bb2, v3 = acc[3] + bb2;
      int m0 = rt * 16 + lkh * 4;
      if (m0 + 0 == del) v0 = 0.f;
      if (m0 + 1 == del) v1 = 0.f;
      if (m0 + 2 == del) v2 = 0.f;
      if (m0 + 3 == del) v3 = 0.f;
      sm += v0 + v1 + v2 + v3;
      sq += v0 * v0 + v1 * v1 + v2 * v2 + v3 * v3;
      u32x2 pk;
      pk.x = cvtpk(v0, v1);
      pk.y = cvtpk(v2, v3);
      *(us4*)(ldsC + (((wrow * 64 + m0) * 2) ^ ((wrow & 7) << 4))) = __builtin_bit_cast(us4, pk);
    }
    sm += __shfl_xor(sm, 16, 64); sm += __shfl_xor(sm, 32, 64);
    sq += __shfl_xor(sq, 16, 64); sq += __shfl_xor(sq, 32, 64);
    if (ln < 16) {
      float* ps = SUB ? p1s + (size_t)bid * 128 : p2s + (size_t)lb * 128;
      float* pq = SUB ? p1q + (size_t)bid * 128 : p2q + (size_t)lb * 128;
      ps[wrow] = sm;
      pq[wrow] = sq;
    }
  }
  __syncthreads();

  // ---- global write hT (linear) ----
  unsigned short* hout = SUB ? h1T + (size_t)bid * 8192 : h2out + (size_t)lb * 8192;
  {
    int e0 = tid * 16;
    int d = e0 >> 6;
    *(us8*)(hout + e0)     = *(const us8*)(ldsC + (((e0)     * 2) ^ ((d & 7) << 4)));
    *(us8*)(hout + e0 + 8) = *(const us8*)(ldsC + (((e0 + 8) * 2) ^ ((d & 7) << 4)));
  }
}

// BN stage-1 reduce, coalesced
__global__ __launch_bounds__(256) void k_bnred(const float* __restrict__ p1s,
    const float* __restrict__ p1q, float* __restrict__ q1s, float* __restrict__ q1q) {
  __shared__ float red[512];
  int b = blockIdx.x, tid = threadIdx.x;
  int d = tid & 127, jh = tid >> 7;
  float s = 0.f, q = 0.f;
  for (int j = b * 64 + jh; j < b * 64 + 64; j += 2) {
    s += p1s[(size_t)j * 128 + d];
    q += p1q[(size_t)j * 128 + d];
  }
  red[tid] = s; red[256 + tid] = q;
  __syncthreads();
  if (tid < 128) {
    q1s[(size_t)b * 128 + d] = red[d] + red[d + 128];
    q1q[(size_t)b * 128 + d] = red[256 + d] + red[384 + d];
  }
}

// Finalize BN into fused scale/shift
__global__ __launch_bounds__(128) void k_bnfin(const float* __restrict__ q1s,
    const float* __restrict__ q1q, const float* __restrict__ p2s,
    const float* __restrict__ p2q, const float* __restrict__ gam1,
    const float* __restrict__ bet1, const float* __restrict__ gam2,
    const float* __restrict__ bet2, float* __restrict__ bnA, float* __restrict__ bnB,
    float* __restrict__ bnsA, float* __restrict__ bnsB) {
  int d = threadIdx.x;
  float s = 0.f, q = 0.f, s2 = 0.f, q2 = 0.f;
  for (int j = 0; j < 64; ++j) {
    s  += q1s[j * 128 + d];  q  += q1q[j * 128 + d];
    s2 += p2s[j * 128 + d];  q2 += p2q[j * 128 + d];
  }
  const float cnt1 = 4096.0f * 63.0f;
  float mean = s / cnt1;
  float var = q / cnt1 - mean * mean;
  float A = gam1[d] * rsqrtf(var + 1e-5f);
  bnA[d] = A; bnB[d] = bet1[d] - mean * A;
  float mean2 = s2 / 4096.0f;
  float var2 = q2 / 4096.0f - mean2 * mean2;
  float A2 = gam2[d] * rsqrtf(var2 + 1e-5f);
  bnsA[d] = A2; bnsB[d] = bet2[d] - mean2 * A2;
}

// final readout MLP per graph, fp32 out
__global__ __launch_bounds__(256) void k_final(const float* __restrict__ ppool,
    const float* __restrict__ W1, const float* __restrict__ b1,
    const float* __restrict__ W2, const float* __restrict__ b2,
    float* __restrict__ out) {
  __shared__ float hg[128];
  __shared__ float z[256];
  int g = blockIdx.x, t = threadIdx.x;
  if (t < 128) {
    float s = ppool[(size_t)(g * 4 + 0) * 128 + t] + ppool[(size_t)(g * 4 + 1) * 128 + t]
            + ppool[(size_t)(g * 4 + 2) * 128 + t] + ppool[(size_t)(g * 4 + 3) * 128 + t];
    hg[t] = s * (1.0f / (63.0f * 64.0f));
  }
  __syncthreads();
  float a = b1[t];
  for (int d = 0; d < 128; ++d) a = fmaf(hg[d], W1[d * 256 + t], a);
  z[t] = lk(a);
  __syncthreads();
  if (t < 10) {
    float o = b2[t];
    for (int j = 0; j < 256; ++j) o = fmaf(z[j], W2[j * 10 + t], o);
    out[g * 10 + t] = o;
  }
}

extern "C" void kernel_launch(void* const* d_in, const int* in_sizes, int n_in,
                              void* d_out, int out_size, void* d_ws, size_t ws_size,
                              hipStream_t stream) {
  (void)in_sizes; (void)n_in; (void)out_size; (void)ws_size;
  const float* x    = (const float*)d_in[0];
  const float* adj  = (const float*)d_in[1];
  const float* oadj = (const float*)d_in[2];
  const float* gW1  = (const float*)d_in[3];
  const float* gb1  = (const float*)d_in[4];
  const float* gW2  = (const float*)d_in[5];
  const float* gb2  = (const float*)d_in[6];
  const float* geps = (const float*)d_in[7];
  const float* sW1  = (const float*)d_in[8];
  const float* sb1  = (const float*)d_in[9];
  const float* sW2  = (const float*)d_in[10];
  const float* sb2  = (const float*)d_in[11];
  const float* seps = (const float*)d_in[12];
  const float* bng  = (const float*)d_in[13];
  const float* bnb  = (const float*)d_in[14];
  const float* bnsg = (const float*)d_in[15];
  const float* bnsb = (const float*)d_in[16];
  const float* fW1  = (const float*)d_in[17];
  const float* fb1  = (const float*)d_in[18];
  const float* fW2  = (const float*)d_in[19];
  const float* fb2  = (const float*)d_in[20];
  float* out = (float*)d_out;

  char* w = (char*)d_ws;
  unsigned short* xw   = (unsigned short*)w; w += 67108864;   // x0 bf16 row-major
  unsigned short* h1T  = (unsigned short*)w; w += 67108864;   // h1 bf16 feature-major
  unsigned short* h2a  = (unsigned short*)w; w += 1048576;    // h2 ping (feature-major)
  unsigned short* h2b  = (unsigned short*)w; w += 1048576;    // h2 pong
  unsigned short* badj = (unsigned short*)w; w += 2097152;    // adj bits
  unsigned short* boadj= (unsigned short*)w; w += 32768;      // oadj bits
  unsigned short* wt   = (unsigned short*)w; w += 524288;     // 16x W^T bf16
  float* pxs  = (float*)w;          w += 8388608;             // xsum partials [256][8192]
  float* p1s  = (float*)w;          w += 2097152;
  float* p1q  = (float*)w;          w += 2097152;
  float* p2s  = (float*)w;          w += 32768;
  float* p2q  = (float*)w;          w += 32768;
  float* q1s  = (float*)w;          w += 32768;
  float* q1q  = (float*)w;          w += 32768;
  float* bnA  = (float*)w;          w += 512;
  float* bnB  = (float*)w;          w += 512;
  float* bnsA = (float*)w;          w += 512;
  float* bnsB = (float*)w;          w += 512;
  float* ppool= (float*)w;          w += 131072;              // [256][128]

  unsigned short* h2buf[2] = {h2a, h2b};

  k_prep<<<16, 256, 0, stream>>>(gW1, gW2, sW1, sW2, wt);
  k_pack<<<4096, 256, 0, stream>>>(adj, badj);
  k_pack<<<64, 256, 0, stream>>>(oadj, boadj);
  k_castseg<<<1024, 256, 0, stream>>>(x, xw, pxs);

  for (int i = 0; i < 4; ++i) {
    unsigned short* h2prev = h2buf[(i + 1) & 1];   // layer i-1 output (i>=1)
    unsigned short* h2cur  = h2buf[i & 1];
    if (i > 0)
      k_xpart<0><<<1024, 256, 0, stream>>>(h1T, h2prev, bnA, bnB, bnsA, bnsB, pxs, ppool);
    if (i == 0)
      k_gin<1><<<4160, 512, 0, stream>>>(xw, h1T, h2prev, h2cur, pxs, badj, boadj,
          wt + 0 * 16384, wt + 1 * 16384, wt + 2 * 16384, wt + 3 * 16384,
          gb1, gb2, sb1, sb2, geps, seps, bnA, bnB, bnsA, bnsB, p1s, p1q, p2s, p2q);
    else
      k_gin<0><<<4160, 512, 0, stream>>>(xw, h1T, h2prev, h2cur, pxs, badj, boadj,
          wt + (i * 4 + 0) * 16384, wt + (i * 4 + 1) * 16384,
          wt + (i * 4 + 2) * 16384, wt + (i * 4 + 3) * 16384,
          gb1 + i * 128, gb2 + i * 128, sb1 + i * 128, sb2 + i * 128,
          geps + i, seps + i, bnA, bnB, bnsA, bnsB, p1s, p1q, p2s, p2q);
    k_bnred<<<64, 256, 0, stream>>>(p1s, p1q, q1s, q1q);
    k_bnfin<<<1, 128, 0, stream>>>(q1s, q1q, p2s, p2q, bng + i * 128,
        bnb + i * 128, bnsg + i * 128, bnsb + i * 128, bnA, bnB, bnsA, bnsB);
  }
  k_xpart<1><<<1024, 256, 0, stream>>>(h1T, h2buf[1], bnA, bnB, bnsA, bnsB, pxs, ppool);
  k_final<<<64, 256, 0, stream>>>(ppool, fW1, fb1, fW2, fb2, out);
}